// Round 7
// baseline (298.740 us; speedup 1.0000x reference)
//
#include <hip/hip_runtime.h>
#include <math.h>

typedef __attribute__((ext_vector_type(8))) short bf16x8;
typedef __attribute__((ext_vector_type(4))) float f32x4;

__device__ __forceinline__ unsigned short f2bf(float f) {
    unsigned u = __builtin_bit_cast(unsigned, f);
    u += 0x7FFF + ((u >> 16) & 1);          // RNE
    return (unsigned short)(u >> 16);
}
__device__ __forceinline__ float bf2f(unsigned short h) {
    unsigned u = ((unsigned)h) << 16;
    return __builtin_bit_cast(float, u);
}

// Packed-weight offsets inside Wb (bf16 elements). Only W8..W11 packed.
#define O_W8 153600
#define O_W9 546816
#define O_W10 1333248
#define O_W11 2119680

// ============================================================================
// MFMA helpers (verified R9/R11/R12 prev session + R2..R6 this session)
// ============================================================================
__device__ __forceinline__ bf16x8 ldcvt8(const float* p) {
    float4 u0 = *(const float4*)p;
    float4 u1 = *(const float4*)(p + 4);
    bf16x8 r;
    r[0] = (short)f2bf(u0.x); r[1] = (short)f2bf(u0.y);
    r[2] = (short)f2bf(u0.z); r[3] = (short)f2bf(u0.w);
    r[4] = (short)f2bf(u1.x); r[5] = (short)f2bf(u1.y);
    r[6] = (short)f2bf(u1.z); r[7] = (short)f2bf(u1.w);
    return r;
}

template<int CIN>
__device__ __forceinline__ void mfma_tile_f32A(
    const float* a0f, const float* a1f,
    const unsigned short* b0p, const unsigned short* b1p,
    f32x4& acc0, f32x4& acc1)
{
#pragma unroll
    for (int k = 0; k < CIN; k += 32) {
        bf16x8 A0 = ldcvt8(a0f + k);
        bf16x8 A1 = ldcvt8(a1f + k);
        bf16x8 B0 = __builtin_bit_cast(bf16x8, *(const float4*)(const void*)(b0p + k));
        bf16x8 B1 = __builtin_bit_cast(bf16x8, *(const float4*)(const void*)(b1p + k));
        acc0 = __builtin_amdgcn_mfma_f32_16x16x32_bf16(A0, B0, acc0, 0, 0, 0);
        acc1 = __builtin_amdgcn_mfma_f32_16x16x32_bf16(A1, B1, acc1, 0, 0, 0);
    }
}

__device__ __forceinline__ void epilogue_store(
    unsigned short* dst, const f32x4& acc0, const f32x4& acc1,
    const float* bias, int fbase, int s0, int s1)
{
    unsigned short o[4];
#pragma unroll
    for (int r = 0; r < 4; ++r) {
        float v = fmaxf(fmaxf(acc0[r] + bias[(fbase + r) * 3 + s0],
                              acc1[r] + bias[(fbase + r) * 3 + s1]), 0.f);
        o[r] = f2bf(v);
    }
    *(ushort4*)dst = make_ushort4(o[0], o[1], o[2], o[3]);
}

// ============================================================================
// fused17: L1..L7 (blocks 0..127, 1024 thr) + pack W8..W11 (blocks 128..191).
// R4-verified body (measured 44.5 us as chain head). All writes idempotent.
// ============================================================================
struct FusedParams {
    const float* x;
    const float* W1; const float* B1; const int* S1;
    const float* W2; const float* B2; const int* S2;
    const float* Wsrc[9];          // W3..W11 fp32
    const float* Bl[9];            // B3..B11
    const int*   Sl[9];            // S3..S11
    unsigned short* Wb;            // packed bf16 (W8..W11 regions)
    unsigned short* X8;            // out: [16][128][256] bf16
};

#define A_SELB 0        //  8192 B: ints[254] @0; floats[1728] @byte 1024
#define A_XS   8192     // 25344 B  f32 [16][3][132]
#define A_L1O  33536    // 16384 B  ush [64][16][8]
#define A_WSM  49920    //  3840 B  f32 W1/B1/W2/B2
#define A_L2O  53760    // 40960 B  ush [32][16][40]   (end 94720)
#define A_L3O  8192     // 36864 B  ush [16][16][72]   (XS/L1O/WSM dead)
#define A_L4O  53760    // 18432 B  ush [8][16][72]    (L2O dead)
#define A_L5O  8192     //  9216 B  ush [4][16][72]    (L3O dead)
#define A_L6O  53760    //  8704 B  ush [2][16][136]   (L4O dead)
#define ARENA_BYTES 94720

__global__ __launch_bounds__(1024) void fused17_kernel(FusedParams P)
{
    const int tid = threadIdx.x;

    if (blockIdx.x >= 128) {
        // ---- pack W8..W11 fp32 -> bf16 (64 blocks x 1024 thr) ----
        int gt = (blockIdx.x - 128) * 1024 + tid;
        const int we[4] = {393216, 786432, 786432, 1572864};
        const int wo[4] = {O_W8, O_W9, O_W10, O_W11};
#pragma unroll
        for (int li = 0; li < 4; ++li) {
            const float4* src = (const float4*)P.Wsrc[5 + li];
            ushort4* dst = (ushort4*)(P.Wb + wo[li]);
            int n4 = we[li] >> 2;
            for (int i = gt; i < n4; i += 65536) {
                float4 w = src[i];
                dst[i] = make_ushort4(f2bf(w.x), f2bf(w.y), f2bf(w.z), f2bf(w.w));
            }
        }
        return;
    }

    __shared__ __align__(16) char arena[ARENA_BYTES];

    const int bg   = blockIdx.x >> 4;      // 0..7  (batch b = bg*16 + 0..15)
    const int sl   = blockIdx.x & 15;      // 0..15 (input pos slice)
    const int lane = tid & 63;
    const int wv   = tid >> 6;             // 0..15
    const int c    = lane & 15, q = lane >> 4;

    int*   si  = (int*)(arena + A_SELB);
    float* bfs = (float*)(arena + A_SELB + 1024);
    const int* S1L = si;           // 128
    const int* S2L = si + 128;     // 64
    const int* S3L = si + 192;     // 32
    const int* S4L = si + 224;     // 16
    const int* S5L = si + 240;     // 8
    const int* S6L = si + 248;     // 4
    const int* S7L = si + 252;     // 2
    const float* B3L = bfs;        // 192
    const float* B4L = bfs + 192;  // 192
    const float* B5L = bfs + 384;  // 192
    const float* B6L = bfs + 576;  // 384
    const float* B7L = bfs + 960;  // 768

    // ---- P0: stage x slice + L1/L2 weights + sels + biases ----
    {
        float* xsf = (float*)(arena + A_XS);
        const float* xg = P.x + (size_t)(bg * 16) * 6144 + sl * 128;
        for (int i = tid; i < 6144; i += 1024) {
            int b = i / 384;
            int r = i - b * 384;
            int cc = r >> 7, p = r & 127;
            xsf[b * 396 + cc * 132 + p] = xg[(size_t)b * 6144 + cc * 2048 + p];
        }
        float* wsm = (float*)(arena + A_WSM);
        if (tid < 960) {
            float v;
            if (tid < 72)       v = P.W1[tid];
            else if (tid < 96)  v = P.B1[tid - 72];
            else if (tid < 864) v = P.W2[tid - 96];
            else                v = P.B2[tid - 864];
            wsm[tid] = v;
        }
        if (tid < 128)      si[tid] = P.S1[sl * 128 + tid];
        else if (tid < 192) si[tid] = P.S2[sl * 64 + (tid - 128)];
        else if (tid < 224) si[tid] = P.Sl[0][sl * 32 + (tid - 192)];
        else if (tid < 240) si[tid] = P.Sl[1][sl * 16 + (tid - 224)];
        else if (tid < 248) si[tid] = P.Sl[2][sl * 8  + (tid - 240)];
        else if (tid < 252) si[tid] = P.Sl[3][sl * 4  + (tid - 248)];
        else if (tid < 254) si[tid] = P.Sl[4][sl * 2  + (tid - 252)];
        for (int i = tid; i < 1728; i += 1024) {
            float v;
            if (i < 192)      v = P.Bl[0][i];
            else if (i < 384) v = P.Bl[1][i - 192];
            else if (i < 576) v = P.Bl[2][i - 384];
            else if (i < 960) v = P.Bl[3][i - 576];
            else              v = P.Bl[4][i - 960];
            bfs[i] = v;
        }
    }
    __syncthreads();

    // ---- P1: L1 (cf=8, cin=3, VALU): 64 pos x 16 b = 1024 items ----
    {
        const float* xsf = (const float*)(arena + A_XS);
        const float* wl1 = (const float*)(arena + A_WSM);
        const float* bl1 = wl1 + 72;
        unsigned short* L1o = (unsigned short*)(arena + A_L1O);
        int n = tid >> 4, b = tid & 15;
        int s0 = S1L[2 * n], s1 = S1L[2 * n + 1];
        const float* xb0 = xsf + b * 396 + 2 * n;
        float c0x = xb0[0],   c0y = xb0[1];
        float c1x = xb0[132], c1y = xb0[133];
        float c2x = xb0[264], c2y = xb0[265];
        unsigned short o[8];
#pragma unroll
        for (int f = 0; f < 8; ++f) {
            int r0 = f * 3 + s0, r1 = f * 3 + s1;
            float z0 = fmaf(wl1[r0*3+2], c2x, fmaf(wl1[r0*3+1], c1x, fmaf(wl1[r0*3+0], c0x, bl1[r0])));
            float z1 = fmaf(wl1[r1*3+2], c2y, fmaf(wl1[r1*3+1], c1y, fmaf(wl1[r1*3+0], c0y, bl1[r1])));
            o[f] = f2bf(fmaxf(fmaxf(z0, z1), 0.f));
        }
        unsigned short* dst = L1o + (n * 16 + b) * 8;
        *(ushort4*)dst       = make_ushort4(o[0], o[1], o[2], o[3]);
        *(ushort4*)(dst + 4) = make_ushort4(o[4], o[5], o[6], o[7]);
    }
    __syncthreads();

    // ---- P2: L2 (cf=32, cin=8, VALU): 32 pos x 16 b x 2 f-halves = 1024 ----
    {
        const float* wl2 = (const float*)(arena + A_WSM) + 96;
        const float* bl2 = (const float*)(arena + A_WSM) + 864;
        const unsigned short* L1o = (const unsigned short*)(arena + A_L1O);
        unsigned short* L2o = (unsigned short*)(arena + A_L2O);
        int n = tid >> 5, b = (tid >> 1) & 15, fh = tid & 1;
        int s0 = S2L[2 * n], s1 = S2L[2 * n + 1];
        const unsigned short* r0 = L1o + ((2 * n) * 16 + b) * 8;
        const unsigned short* r1 = L1o + ((2 * n + 1) * 16 + b) * 8;
        float xa[8], xb2[8];
        {
            ushort4 u0 = *(const ushort4*)r0, u1 = *(const ushort4*)(r0 + 4);
            ushort4 v0 = *(const ushort4*)r1, v1 = *(const ushort4*)(r1 + 4);
            xa[0]=bf2f(u0.x); xa[1]=bf2f(u0.y); xa[2]=bf2f(u0.z); xa[3]=bf2f(u0.w);
            xa[4]=bf2f(u1.x); xa[5]=bf2f(u1.y); xa[6]=bf2f(u1.z); xa[7]=bf2f(u1.w);
            xb2[0]=bf2f(v0.x); xb2[1]=bf2f(v0.y); xb2[2]=bf2f(v0.z); xb2[3]=bf2f(v0.w);
            xb2[4]=bf2f(v1.x); xb2[5]=bf2f(v1.y); xb2[6]=bf2f(v1.z); xb2[7]=bf2f(v1.w);
        }
        unsigned short o[16];
#pragma unroll
        for (int fl = 0; fl < 16; ++fl) {
            int f = fh * 16 + fl;
            const float* w0 = &wl2[(f * 3 + s0) * 8];
            const float* w1 = &wl2[(f * 3 + s1) * 8];
            float z0 = bl2[f * 3 + s0], z1 = bl2[f * 3 + s1];
#pragma unroll
            for (int k = 0; k < 8; ++k) {
                z0 = fmaf(w0[k], xa[k], z0);
                z1 = fmaf(w1[k], xb2[k], z1);
            }
            o[fl] = f2bf(fmaxf(fmaxf(z0, z1), 0.f));
        }
        unsigned short* dst = L2o + (n * 16 + b) * 40 + fh * 16;
#pragma unroll
        for (int i2 = 0; i2 < 4; ++i2)
            *(ushort4*)(dst + 4 * i2) = make_ushort4(o[4*i2], o[4*i2+1], o[4*i2+2], o[4*i2+3]);
    }
    __syncthreads();

    // ---- P3: L3 (cf=64, cin=32): 64 tasks, 4 rounds ----
    {
        const unsigned short* L2o = (const unsigned short*)(arena + A_L2O);
        unsigned short* L3o = (unsigned short*)(arena + A_L3O);
        const float* W3f = P.Wsrc[0];
#pragma unroll 2
        for (int t = wv; t < 64; t += 16) {
            int n3 = t >> 2, ft = t & 3;
            int s0 = __builtin_amdgcn_readfirstlane(S3L[2 * n3]);
            int s1 = __builtin_amdgcn_readfirstlane(S3L[2 * n3 + 1]);
            int f0 = ft * 16;
            const float* a0f = W3f + ((f0 + c) * 3 + s0) * 32 + q * 8;
            const float* a1f = W3f + ((f0 + c) * 3 + s1) * 32 + q * 8;
            const unsigned short* bp0 = L2o + ((2 * n3) * 16 + c) * 40 + q * 8;
            const unsigned short* bp1 = L2o + ((2 * n3 + 1) * 16 + c) * 40 + q * 8;
            f32x4 acc0 = {0.f,0.f,0.f,0.f}, acc1 = {0.f,0.f,0.f,0.f};
            mfma_tile_f32A<32>(a0f, a1f, bp0, bp1, acc0, acc1);
            epilogue_store(L3o + (n3 * 16 + c) * 72 + f0 + q * 4,
                           acc0, acc1, B3L, f0 + q * 4, s0, s1);
        }
    }
    __syncthreads();

    // ---- P4: L4 (cf=64, cin=64): 32 tasks, 2 rounds ----
    {
        const unsigned short* L3o = (const unsigned short*)(arena + A_L3O);
        unsigned short* L4o = (unsigned short*)(arena + A_L4O);
        const float* W4f = P.Wsrc[1];
#pragma unroll
        for (int t = wv; t < 32; t += 16) {
            int n4 = t >> 2, ft = t & 3;
            int s0 = __builtin_amdgcn_readfirstlane(S4L[2 * n4]);
            int s1 = __builtin_amdgcn_readfirstlane(S4L[2 * n4 + 1]);
            int f0 = ft * 16;
            const float* a0f = W4f + ((f0 + c) * 3 + s0) * 64 + q * 8;
            const float* a1f = W4f + ((f0 + c) * 3 + s1) * 64 + q * 8;
            const unsigned short* bp0 = L3o + ((2 * n4) * 16 + c) * 72 + q * 8;
            const unsigned short* bp1 = L3o + ((2 * n4 + 1) * 16 + c) * 72 + q * 8;
            f32x4 acc0 = {0.f,0.f,0.f,0.f}, acc1 = {0.f,0.f,0.f,0.f};
            mfma_tile_f32A<64>(a0f, a1f, bp0, bp1, acc0, acc1);
            epilogue_store(L4o + (n4 * 16 + c) * 72 + f0 + q * 4,
                           acc0, acc1, B4L, f0 + q * 4, s0, s1);
        }
    }
    __syncthreads();

    // ---- P5: L5 (cf=64, cin=64): 16 tasks, 1 round ----
    {
        const unsigned short* L4o = (const unsigned short*)(arena + A_L4O);
        unsigned short* L5o = (unsigned short*)(arena + A_L5O);
        const float* W5f = P.Wsrc[2];
        int t = wv;
        int n5 = t >> 2, ft = t & 3;
        int s0 = __builtin_amdgcn_readfirstlane(S5L[2 * n5]);
        int s1 = __builtin_amdgcn_readfirstlane(S5L[2 * n5 + 1]);
        int f0 = ft * 16;
        const float* a0f = W5f + ((f0 + c) * 3 + s0) * 64 + q * 8;
        const float* a1f = W5f + ((f0 + c) * 3 + s1) * 64 + q * 8;
        const unsigned short* bp0 = L4o + ((2 * n5) * 16 + c) * 72 + q * 8;
        const unsigned short* bp1 = L4o + ((2 * n5 + 1) * 16 + c) * 72 + q * 8;
        f32x4 acc0 = {0.f,0.f,0.f,0.f}, acc1 = {0.f,0.f,0.f,0.f};
        mfma_tile_f32A<64>(a0f, a1f, bp0, bp1, acc0, acc1);
        epilogue_store(L5o + (n5 * 16 + c) * 72 + f0 + q * 4,
                       acc0, acc1, B5L, f0 + q * 4, s0, s1);
    }
    __syncthreads();

    // ---- P6: L6 (cf=128, cin=64): 16 tasks, 1 round ----
    {
        const unsigned short* L5o = (const unsigned short*)(arena + A_L5O);
        unsigned short* L6o = (unsigned short*)(arena + A_L6O);
        const float* W6f = P.Wsrc[3];
        int t = wv;
        int n6 = t >> 3, ft = t & 7;
        int s0 = __builtin_amdgcn_readfirstlane(S6L[2 * n6]);
        int s1 = __builtin_amdgcn_readfirstlane(S6L[2 * n6 + 1]);
        int f0 = ft * 16;
        const float* a0f = W6f + ((f0 + c) * 3 + s0) * 64 + q * 8;
        const float* a1f = W6f + ((f0 + c) * 3 + s1) * 64 + q * 8;
        const unsigned short* bp0 = L5o + ((2 * n6) * 16 + c) * 72 + q * 8;
        const unsigned short* bp1 = L5o + ((2 * n6 + 1) * 16 + c) * 72 + q * 8;
        f32x4 acc0 = {0.f,0.f,0.f,0.f}, acc1 = {0.f,0.f,0.f,0.f};
        mfma_tile_f32A<64>(a0f, a1f, bp0, bp1, acc0, acc1);
        epilogue_store(L6o + (n6 * 16 + c) * 136 + f0 + q * 4,
                       acc0, acc1, B6L, f0 + q * 4, s0, s1);
    }
    __syncthreads();

    // ---- P7: L7 (cf=256, cin=128): 16 ftiles, 1 round; out to global ----
    {
        const unsigned short* L6o = (const unsigned short*)(arena + A_L6O);
        const float* W7f = P.Wsrc[4];
        int s0 = __builtin_amdgcn_readfirstlane(S7L[0]);
        int s1 = __builtin_amdgcn_readfirstlane(S7L[1]);
        int f0 = wv * 16;
        const float* a0f = W7f + (size_t)((f0 + c) * 3 + s0) * 128 + q * 8;
        const float* a1f = W7f + (size_t)((f0 + c) * 3 + s1) * 128 + q * 8;
        const unsigned short* bp0 = L6o + (0 * 16 + c) * 136 + q * 8;
        const unsigned short* bp1 = L6o + (1 * 16 + c) * 136 + q * 8;
        f32x4 acc0 = {0.f,0.f,0.f,0.f}, acc1 = {0.f,0.f,0.f,0.f};
        mfma_tile_f32A<128>(a0f, a1f, bp0, bp1, acc0, acc1);
        epilogue_store(P.X8 + ((size_t)sl * 128 + bg * 16 + c) * 256 + f0 + q * 4,
                       acc0, acc1, B7L, f0 + q * 4, s0, s1);
    }
}

// ============================================================================
// Flat MFMA layer (L8..L11): verified R9 body (R0 verbatim).
// ============================================================================
template<int CIN, int CF, int NP, int MW, int NW>
__global__ __launch_bounds__(256) void mfma_kernel(
    const unsigned short* __restrict__ Xin,
    const unsigned short* __restrict__ Wb,
    const float* __restrict__ bias,
    const int*   __restrict__ sel,
    unsigned short* __restrict__ Xout)
{
    constexpr int FT = CF / (16 * MW);
    constexpr int BT = 128 / (16 * NW);

    const int wid  = threadIdx.x >> 6;
    const int lane = threadIdx.x & 63;
    const int task = blockIdx.x * 4 + wid;
    const int bi = task % BT;
    const int fi = (task / BT) % FT;
    const int n  = task / (BT * FT);

    const int c = lane & 15;
    const int q = lane >> 4;
    const int s0 = __builtin_amdgcn_readfirstlane(sel[2 * n]);
    const int s1 = __builtin_amdgcn_readfirstlane(sel[2 * n + 1]);

    const int f0 = fi * 16 * MW;
    const int b0 = bi * 16 * NW;

    const unsigned short* ap[2][MW];
    const unsigned short* bp[2][NW];
#pragma unroll
    for (int p = 0; p < 2; ++p) {
        int s = p ? s1 : s0;
#pragma unroll
        for (int mi = 0; mi < MW; ++mi)
            ap[p][mi] = Wb + (size_t)((f0 + mi * 16 + c) * 3 + s) * CIN + q * 8;
#pragma unroll
        for (int ni = 0; ni < NW; ++ni)
            bp[p][ni] = Xin + ((size_t)(2 * n + p) * 128 + b0 + ni * 16 + c) * CIN + q * 8;
    }

    f32x4 acc[2][MW][NW];
#pragma unroll
    for (int p = 0; p < 2; ++p)
#pragma unroll
        for (int mi = 0; mi < MW; ++mi)
#pragma unroll
            for (int ni = 0; ni < NW; ++ni)
                acc[p][mi][ni] = (f32x4){0.f, 0.f, 0.f, 0.f};

#pragma unroll 2
    for (int k = 0; k < CIN; k += 32) {
        bf16x8 A[2][MW], B[2][NW];
#pragma unroll
        for (int p = 0; p < 2; ++p) {
#pragma unroll
            for (int mi = 0; mi < MW; ++mi)
                A[p][mi] = __builtin_bit_cast(bf16x8, *(const float4*)(const void*)(ap[p][mi] + k));
#pragma unroll
            for (int ni = 0; ni < NW; ++ni)
                B[p][ni] = __builtin_bit_cast(bf16x8, *(const float4*)(const void*)(bp[p][ni] + k));
        }
#pragma unroll
        for (int p = 0; p < 2; ++p)
#pragma unroll
            for (int mi = 0; mi < MW; ++mi)
#pragma unroll
                for (int ni = 0; ni < NW; ++ni)
                    acc[p][mi][ni] = __builtin_amdgcn_mfma_f32_16x16x32_bf16(
                        A[p][mi], B[p][ni], acc[p][mi][ni], 0, 0, 0);
    }

#pragma unroll
    for (int mi = 0; mi < MW; ++mi) {
        int fbase = f0 + mi * 16 + q * 4;
#pragma unroll
        for (int ni = 0; ni < NW; ++ni) {
            int b = b0 + ni * 16 + c;
            epilogue_store(Xout + ((size_t)n * 128 + b) * CF + fbase,
                           acc[0][mi][ni], acc[1][mi][ni], bias, fbase, s0, s1);
        }
    }
}

// ============================================================================
// FC head: h bf16 [128][1024]; out [128][16] fp32 log-softmax (R0 verbatim)
// ============================================================================
__global__ __launch_bounds__(256) void fc_logsoftmax_kernel(
    const unsigned short* __restrict__ h, const float* __restrict__ fcW,
    const float* __restrict__ fcb, float* __restrict__ out)
{
    int b   = blockIdx.x;
    int tid = threadIdx.x;
    int k     = tid & 15;
    int chunk = tid >> 4;

    const float* __restrict__ wk = fcW + (size_t)k * 1024;
    const unsigned short* hb = h + (size_t)b * 1024;

    float partial = 0.0f;
    int j0 = chunk * 64;
#pragma unroll 8
    for (int j = 0; j < 64; ++j)
        partial = fmaf(bf2f(hb[j0 + j]), wk[j0 + j], partial);

    __shared__ float red[16][17];
    red[chunk][k] = partial;
    __syncthreads();

    __shared__ float logits[16];
    if (tid < 16) {
        float s = fcb[tid];
#pragma unroll
        for (int c = 0; c < 16; ++c) s += red[c][tid];
        logits[tid] = s;
    }
    __syncthreads();

    if (tid < 16) {
        float mx = -INFINITY;
#pragma unroll
        for (int kk = 0; kk < 16; ++kk) mx = fmaxf(mx, logits[kk]);
        float se = 0.0f;
#pragma unroll
        for (int kk = 0; kk < 16; ++kk) se += expf(logits[kk] - mx);
        out[b * 16 + tid] = logits[tid] - mx - logf(se);
    }
}

// ============================================================================
// R7 EXPERIMENT: run the ENTIRE chain twice. All writes are idempotent
// (deterministic kernels, same inputs -> same values), so pass #1 is a
// correctness-neutral warm-up that absorbs cold-I$/cold-data/fill-drain;
// pass #2 measures the warm cost of the identical chain.
// ============================================================================
extern "C" void kernel_launch(void* const* d_in, const int* in_sizes, int n_in,
                              void* d_out, int out_size, void* d_ws, size_t ws_size,
                              hipStream_t stream)
{
#define WL(i) (const float*)d_in[1 + 3 * (i)]
#define BL(i) (const float*)d_in[2 + 3 * (i)]
#define SL(i) (const int*)  d_in[3 + 3 * (i)]

    unsigned short* bufA = (unsigned short*)d_ws;          // 4 MB
    unsigned short* bufB = bufA + 2u * 1024u * 1024u;      // 4 MB
    unsigned short* Wb   = bufB + 2u * 1024u * 1024u;      // packed bf16 (W8..W11)

    FusedParams FP;
    FP.x  = (const float*)d_in[0];
    FP.W1 = WL(0); FP.B1 = BL(0); FP.S1 = SL(0);
    FP.W2 = WL(1); FP.B2 = BL(1); FP.S2 = SL(1);
    for (int i = 0; i < 9; ++i) {
        FP.Wsrc[i] = WL(2 + i);
        FP.Bl[i]   = BL(2 + i);
        FP.Sl[i]   = SL(2 + i);
    }
    FP.Wb = Wb; FP.X8 = bufA;

    for (int rep = 0; rep < 2; ++rep) {
        // ---- fused L1..L7 -> X8 (bufA)  ||  pack W8..W11 -> Wb ----
        fused17_kernel<<<192, 1024, 0, stream>>>(FP);

        // ---- flat MFMA layers L8..L11 (R0-verified configs) ----
        mfma_kernel<256, 512, 8, 2, 2><<<128, 256, 0, stream>>>(bufA, Wb + O_W8,  BL(7),  SL(7),  bufB);
        mfma_kernel<512, 512, 4, 1, 1><<<256, 256, 0, stream>>>(bufB, Wb + O_W9,  BL(8),  SL(8),  bufA);
        mfma_kernel<512, 512, 2, 1, 1><<<128, 256, 0, stream>>>(bufA, Wb + O_W10, BL(9),  SL(9),  bufB);
        mfma_kernel<512, 1024, 1, 1, 1><<<128, 256, 0, stream>>>(bufB, Wb + O_W11, BL(10), SL(10), bufA);

        // ---- FC ----
        fc_logsoftmax_kernel<<<128, 256, 0, stream>>>(bufA, (const float*)d_in[34], (const float*)d_in[35], (float*)d_out);
    }

#undef WL
#undef BL
#undef SL
}

// Round 8
// 216.264 us; speedup vs baseline: 1.3814x; 1.3814x over previous
//
#include <hip/hip_runtime.h>
#include <math.h>

typedef __attribute__((ext_vector_type(8))) short bf16x8;
typedef __attribute__((ext_vector_type(4))) float f32x4;

__device__ __forceinline__ unsigned short f2bf(float f) {
    unsigned u = __builtin_bit_cast(unsigned, f);
    u += 0x7FFF + ((u >> 16) & 1);          // RNE
    return (unsigned short)(u >> 16);
}
__device__ __forceinline__ float bf2f(unsigned short h) {
    unsigned u = ((unsigned)h) << 16;
    return __builtin_bit_cast(float, u);
}

// Packed-weight offsets inside Wb (bf16 elements). Only W8..W11 packed.
#define O_W8 153600
#define O_W9 546816
#define O_W10 1333248
#define O_W11 2119680

// ============================================================================
// MFMA helpers (verified across prev session + R2..R7)
// ============================================================================
__device__ __forceinline__ bf16x8 ldcvt8(const float* p) {
    float4 u0 = *(const float4*)p;
    float4 u1 = *(const float4*)(p + 4);
    bf16x8 r;
    r[0] = (short)f2bf(u0.x); r[1] = (short)f2bf(u0.y);
    r[2] = (short)f2bf(u0.z); r[3] = (short)f2bf(u0.w);
    r[4] = (short)f2bf(u1.x); r[5] = (short)f2bf(u1.y);
    r[6] = (short)f2bf(u1.z); r[7] = (short)f2bf(u1.w);
    return r;
}

template<int CIN>
__device__ __forceinline__ void mfma_tile_f32A(
    const float* a0f, const float* a1f,
    const unsigned short* b0p, const unsigned short* b1p,
    f32x4& acc0, f32x4& acc1)
{
#pragma unroll
    for (int k = 0; k < CIN; k += 32) {
        bf16x8 A0 = ldcvt8(a0f + k);
        bf16x8 A1 = ldcvt8(a1f + k);
        bf16x8 B0 = __builtin_bit_cast(bf16x8, *(const float4*)(const void*)(b0p + k));
        bf16x8 B1 = __builtin_bit_cast(bf16x8, *(const float4*)(const void*)(b1p + k));
        acc0 = __builtin_amdgcn_mfma_f32_16x16x32_bf16(A0, B0, acc0, 0, 0, 0);
        acc1 = __builtin_amdgcn_mfma_f32_16x16x32_bf16(A1, B1, acc1, 0, 0, 0);
    }
}

__device__ __forceinline__ void epilogue_store(
    unsigned short* dst, const f32x4& acc0, const f32x4& acc1,
    const float* bias, int fbase, int s0, int s1)
{
    unsigned short o[4];
#pragma unroll
    for (int r = 0; r < 4; ++r) {
        float v = fmaxf(fmaxf(acc0[r] + bias[(fbase + r) * 3 + s0],
                              acc1[r] + bias[(fbase + r) * 3 + s1]), 0.f);
        o[r] = f2bf(v);
    }
    *(ushort4*)dst = make_ushort4(o[0], o[1], o[2], o[3]);
}

// ============================================================================
// HEAD (R8, new shape): streaming L1+L2 with NO inter-wave coupling.
//   blocks 0..255  : 4 waves each -> 1024 independent waves.
//     wave gw: b = gw>>3 (0..127), chunk = gw&7; lane owns np2 = chunk*64+lane.
//     One float4 x-load per channel delivers EXACTLY the lane's 4 input
//     positions [4*np2, 4*np2+4). sel via coalesced int4/int2. L1 result kept
//     in regs WITH bf16 round-trip (bit-identical to the R6-passing chain).
//     Out: X3[np2][b][0..32) bf16.
//   blocks 256..511: pack W8..W11 fp32->bf16 (R5-proven streaming shape) and
//     touch W3..W7 into L3 (keepalive, rule #17) for kb_l37.
// Single barrier (weight stage); no LDS intermediates; no serial phases.
// ============================================================================
struct HeadParams {
    const float* x;
    const float* W1; const float* B1; const int* S1;
    const float* W2; const float* B2; const int* S2;
    const float* Wsrc[9];          // W3..W11 fp32
    unsigned short* Wb;
    unsigned short* X3;            // [512][128][32]
};

__global__ __launch_bounds__(256) void head_l12_pack(HeadParams P)
{
    const int tid = threadIdx.x;

    if (blockIdx.x >= 256) {
        // ---- pack W8..W11 (21 MB stream) ----
        int gt = (blockIdx.x - 256) * 256 + tid;      // 0..65535
        const int we[4] = {393216, 786432, 786432, 1572864};
        const int wo[4] = {O_W8, O_W9, O_W10, O_W11};
#pragma unroll
        for (int li = 0; li < 4; ++li) {
            const float4* src = (const float4*)P.Wsrc[5 + li];
            ushort4* dst = (ushort4*)(P.Wb + wo[li]);
            int n4 = we[li] >> 2;
            for (int i = gt; i < n4; i += 65536) {
                float4 w = src[i];
                dst[i] = make_ushort4(f2bf(w.x), f2bf(w.y), f2bf(w.z), f2bf(w.w));
            }
        }
        // ---- touch W3..W7 into L3 for kb_l37 (keepalive, no store) ----
        float4 acc = {0.f, 0.f, 0.f, 0.f};
        const int wn[5] = {6144, 12288, 12288, 24576, 98304};
#pragma unroll
        for (int li = 0; li < 5; ++li) {
            const float4* src = (const float4*)P.Wsrc[li];
            int n4 = wn[li] >> 2;
            for (int i = gt; i < n4; i += 65536) {
                float4 v = src[i];
                acc.x += v.x; acc.y += v.y; acc.z += v.z; acc.w += v.w;
            }
        }
        float s = acc.x + acc.y + acc.z + acc.w;
        asm volatile("" :: "v"(s));
        return;
    }

    // ---- stage L1/L2 weights (3.75 KB), one barrier ----
    __shared__ float wsm[960];
    for (int i = tid; i < 960; i += 256) {
        float v;
        if (i < 72)       v = P.W1[i];
        else if (i < 96)  v = P.B1[i - 72];
        else if (i < 864) v = P.W2[i - 96];
        else              v = P.B2[i - 864];
        wsm[i] = v;
    }
    __syncthreads();

    const float* wl1 = wsm;
    const float* bl1 = wsm + 72;
    const float* wl2 = wsm + 96;
    const float* bl2 = wsm + 864;

    const int lane = tid & 63;
    const int gw   = blockIdx.x * 4 + (tid >> 6);   // 0..1023
    const int b    = gw >> 3;                        // 0..127
    const int chunk= gw & 7;                         // 0..7
    const int np2  = chunk * 64 + lane;              // 0..511

    // ---- coalesced loads: x (3 x float4), sel (int4 + int2) ----
    const float* xb = P.x + (size_t)b * 6144 + chunk * 256 + 4 * lane;
    float4 x0 = *(const float4*)(xb);            // ch0, positions 4np2..+3
    float4 x1 = *(const float4*)(xb + 2048);     // ch1
    float4 x2 = *(const float4*)(xb + 4096);     // ch2
    int4 sA = *(const int4*)(P.S1 + 4 * np2);    // S1[4np2..4np2+3]
    int2 sB = *(const int2*)(P.S2 + 2 * np2);    // S2[2np2..2np2+1]

    // ---- L1 (cf=8, cin=3) for np1a=2np2 (x idx 0,1) and np1b=2np2+1 (2,3).
    //      bf16 round-trip preserved for bit-identical numerics. ----
    float y1a[8], y1b[8];
    {
        int s0 = sA.x, s1 = sA.y;          // np1a: sel at pos 4np2, 4np2+1
#pragma unroll
        for (int f = 0; f < 8; ++f) {
            int r0 = f * 3 + s0, r1 = f * 3 + s1;
            float z0 = fmaf(wl1[r0*3+2], x2.x, fmaf(wl1[r0*3+1], x1.x, fmaf(wl1[r0*3+0], x0.x, bl1[r0])));
            float z1 = fmaf(wl1[r1*3+2], x2.y, fmaf(wl1[r1*3+1], x1.y, fmaf(wl1[r1*3+0], x0.y, bl1[r1])));
            y1a[f] = bf2f(f2bf(fmaxf(fmaxf(z0, z1), 0.f)));
        }
        int t0 = sA.z, t1 = sA.w;          // np1b: sel at pos 4np2+2, 4np2+3
#pragma unroll
        for (int f = 0; f < 8; ++f) {
            int r0 = f * 3 + t0, r1 = f * 3 + t1;
            float z0 = fmaf(wl1[r0*3+2], x2.z, fmaf(wl1[r0*3+1], x1.z, fmaf(wl1[r0*3+0], x0.z, bl1[r0])));
            float z1 = fmaf(wl1[r1*3+2], x2.w, fmaf(wl1[r1*3+1], x1.w, fmaf(wl1[r1*3+0], x0.w, bl1[r1])));
            y1b[f] = bf2f(f2bf(fmaxf(fmaxf(z0, z1), 0.f)));
        }
    }

    // ---- L2 (cf=32, cin=8): 32 features, out bf16 ----
    unsigned short o[32];
    {
        int s0 = sB.x, s1 = sB.y;
#pragma unroll
        for (int f = 0; f < 32; ++f) {
            const float* w0 = &wl2[(f * 3 + s0) * 8];
            const float* w1 = &wl2[(f * 3 + s1) * 8];
            float z0 = bl2[f * 3 + s0], z1 = bl2[f * 3 + s1];
#pragma unroll
            for (int k = 0; k < 8; ++k) {
                z0 = fmaf(w0[k], y1a[k], z0);
                z1 = fmaf(w1[k], y1b[k], z1);
            }
            o[f] = f2bf(fmaxf(fmaxf(z0, z1), 0.f));
        }
    }

    // ---- write X3[np2][b][0..32): 64 B contiguous per lane ----
    unsigned short* dst = P.X3 + ((size_t)np2 * 128 + b) * 32;
#pragma unroll
    for (int i2 = 0; i2 < 8; ++i2)
        *(ushort4*)(dst + 4 * i2) = make_ushort4(o[4*i2], o[4*i2+1], o[4*i2+2], o[4*i2+3]);
}

// ============================================================================
// kB: L3..L7 (VERBATIM R6-passing body). 128 blocks x 512 thr.
// Reads X3 [512][128][32]; LDS chain; writes X8 [16][128][256].
// ============================================================================
struct KBParams {
    const float* Wsrc[9];
    const float* Bl[9];
    const int*   Sl[9];
    const unsigned short* X3;
    unsigned short* X8;
};

#define B_SELB 0        //  8192 B: ints[62] @0; floats[1728] @byte 1024
#define B_L3O  8192     // 36864 B  ush [16][16][72]   (end 45056)
#define B_L4O  45056    // 18432 B  ush [8][16][72]    (end 63488)
#define B_L5O  8192     //  9216 B  ush [4][16][72]    (L3O dead)
#define B_L6O  45056    //  8704 B  ush [2][16][136]   (L4O dead)
#define B_ARENA 63488

__global__ __launch_bounds__(512) void kb_l37(KBParams P)
{
    __shared__ __align__(16) char arena[B_ARENA];

    const int tid  = threadIdx.x;
    const int bg   = blockIdx.x >> 4;
    const int sl   = blockIdx.x & 15;
    const int lane = tid & 63;
    const int wv   = tid >> 6;             // 0..7
    const int c    = lane & 15, q = lane >> 4;

    int*   si  = (int*)(arena + B_SELB);
    float* bfs = (float*)(arena + B_SELB + 1024);
    const int* S3L = si;          // 32
    const int* S4L = si + 32;     // 16
    const int* S5L = si + 48;     // 8
    const int* S6L = si + 56;     // 4
    const int* S7L = si + 60;     // 2
    const float* B3L = bfs;        // 192
    const float* B4L = bfs + 192;  // 192
    const float* B5L = bfs + 384;  // 192
    const float* B6L = bfs + 576;  // 384
    const float* B7L = bfs + 960;  // 768

    if (tid < 32)       si[tid] = P.Sl[0][sl * 32 + tid];
    else if (tid < 48)  si[tid] = P.Sl[1][sl * 16 + (tid - 32)];
    else if (tid < 56)  si[tid] = P.Sl[2][sl * 8 + (tid - 48)];
    else if (tid < 60)  si[tid] = P.Sl[3][sl * 4 + (tid - 56)];
    else if (tid < 62)  si[tid] = P.Sl[4][sl * 2 + (tid - 60)];
    for (int i = tid; i < 1728; i += 512) {
        float v;
        if (i < 192)      v = P.Bl[0][i];
        else if (i < 384) v = P.Bl[1][i - 192];
        else if (i < 576) v = P.Bl[2][i - 384];
        else if (i < 960) v = P.Bl[3][i - 576];
        else              v = P.Bl[4][i - 960];
        bfs[i] = v;
    }
    __syncthreads();

    // ---- L3 (cf=64, cin=32): 64 tasks, 8 rounds ----
    {
        unsigned short* L3o = (unsigned short*)(arena + B_L3O);
        const float* W3f = P.Wsrc[0];
#pragma unroll 2
        for (int t = wv; t < 64; t += 8) {
            int n3 = t >> 2, ft = t & 3;
            int s0 = __builtin_amdgcn_readfirstlane(S3L[2 * n3]);
            int s1 = __builtin_amdgcn_readfirstlane(S3L[2 * n3 + 1]);
            int f0 = ft * 16;
            const float* a0f = W3f + ((f0 + c) * 3 + s0) * 32 + q * 8;
            const float* a1f = W3f + ((f0 + c) * 3 + s1) * 32 + q * 8;
            const unsigned short* bp0 = P.X3 + ((size_t)(sl * 32 + 2 * n3) * 128 + bg * 16 + c) * 32 + q * 8;
            const unsigned short* bp1 = P.X3 + ((size_t)(sl * 32 + 2 * n3 + 1) * 128 + bg * 16 + c) * 32 + q * 8;
            f32x4 acc0 = {0.f,0.f,0.f,0.f}, acc1 = {0.f,0.f,0.f,0.f};
            mfma_tile_f32A<32>(a0f, a1f, bp0, bp1, acc0, acc1);
            epilogue_store(L3o + (n3 * 16 + c) * 72 + f0 + q * 4,
                           acc0, acc1, B3L, f0 + q * 4, s0, s1);
        }
    }
    __syncthreads();

    // ---- L4 (cf=64, cin=64): 32 tasks, 4 rounds ----
    {
        const unsigned short* L3o = (const unsigned short*)(arena + B_L3O);
        unsigned short* L4o = (unsigned short*)(arena + B_L4O);
        const float* W4f = P.Wsrc[1];
#pragma unroll 2
        for (int t = wv; t < 32; t += 8) {
            int n4 = t >> 2, ft = t & 3;
            int s0 = __builtin_amdgcn_readfirstlane(S4L[2 * n4]);
            int s1 = __builtin_amdgcn_readfirstlane(S4L[2 * n4 + 1]);
            int f0 = ft * 16;
            const float* a0f = W4f + ((f0 + c) * 3 + s0) * 64 + q * 8;
            const float* a1f = W4f + ((f0 + c) * 3 + s1) * 64 + q * 8;
            const unsigned short* bp0 = L3o + ((2 * n4) * 16 + c) * 72 + q * 8;
            const unsigned short* bp1 = L3o + ((2 * n4 + 1) * 16 + c) * 72 + q * 8;
            f32x4 acc0 = {0.f,0.f,0.f,0.f}, acc1 = {0.f,0.f,0.f,0.f};
            mfma_tile_f32A<64>(a0f, a1f, bp0, bp1, acc0, acc1);
            epilogue_store(L4o + (n4 * 16 + c) * 72 + f0 + q * 4,
                           acc0, acc1, B4L, f0 + q * 4, s0, s1);
        }
    }
    __syncthreads();

    // ---- L5 (cf=64, cin=64): 16 tasks, 2 rounds ----
    {
        const unsigned short* L4o = (const unsigned short*)(arena + B_L4O);
        unsigned short* L5o = (unsigned short*)(arena + B_L5O);
        const float* W5f = P.Wsrc[2];
#pragma unroll
        for (int t = wv; t < 16; t += 8) {
            int n5 = t >> 2, ft = t & 3;
            int s0 = __builtin_amdgcn_readfirstlane(S5L[2 * n5]);
            int s1 = __builtin_amdgcn_readfirstlane(S5L[2 * n5 + 1]);
            int f0 = ft * 16;
            const float* a0f = W5f + ((f0 + c) * 3 + s0) * 64 + q * 8;
            const float* a1f = W5f + ((f0 + c) * 3 + s1) * 64 + q * 8;
            const unsigned short* bp0 = L4o + ((2 * n5) * 16 + c) * 72 + q * 8;
            const unsigned short* bp1 = L4o + ((2 * n5 + 1) * 16 + c) * 72 + q * 8;
            f32x4 acc0 = {0.f,0.f,0.f,0.f}, acc1 = {0.f,0.f,0.f,0.f};
            mfma_tile_f32A<64>(a0f, a1f, bp0, bp1, acc0, acc1);
            epilogue_store(L5o + (n5 * 16 + c) * 72 + f0 + q * 4,
                           acc0, acc1, B5L, f0 + q * 4, s0, s1);
        }
    }
    __syncthreads();

    // ---- L6 (cf=128, cin=64): 16 tasks, 2 rounds ----
    {
        const unsigned short* L5o = (const unsigned short*)(arena + B_L5O);
        unsigned short* L6o = (unsigned short*)(arena + B_L6O);
        const float* W6f = P.Wsrc[3];
#pragma unroll
        for (int t = wv; t < 16; t += 8) {
            int n6 = t >> 3, ft = t & 7;
            int s0 = __builtin_amdgcn_readfirstlane(S6L[2 * n6]);
            int s1 = __builtin_amdgcn_readfirstlane(S6L[2 * n6 + 1]);
            int f0 = ft * 16;
            const float* a0f = W6f + ((f0 + c) * 3 + s0) * 64 + q * 8;
            const float* a1f = W6f + ((f0 + c) * 3 + s1) * 64 + q * 8;
            const unsigned short* bp0 = L5o + ((2 * n6) * 16 + c) * 72 + q * 8;
            const unsigned short* bp1 = L5o + ((2 * n6 + 1) * 16 + c) * 72 + q * 8;
            f32x4 acc0 = {0.f,0.f,0.f,0.f}, acc1 = {0.f,0.f,0.f,0.f};
            mfma_tile_f32A<64>(a0f, a1f, bp0, bp1, acc0, acc1);
            epilogue_store(L6o + (n6 * 16 + c) * 136 + f0 + q * 4,
                           acc0, acc1, B6L, f0 + q * 4, s0, s1);
        }
    }
    __syncthreads();

    // ---- L7 (cf=256, cin=128): 16 ftiles, 2 rounds; out to global ----
    {
        const unsigned short* L6o = (const unsigned short*)(arena + B_L6O);
        const float* W7f = P.Wsrc[4];
        int s0 = __builtin_amdgcn_readfirstlane(S7L[0]);
        int s1 = __builtin_amdgcn_readfirstlane(S7L[1]);
#pragma unroll
        for (int t = wv; t < 16; t += 8) {
            int f0 = t * 16;
            const float* a0f = W7f + (size_t)((f0 + c) * 3 + s0) * 128 + q * 8;
            const float* a1f = W7f + (size_t)((f0 + c) * 3 + s1) * 128 + q * 8;
            const unsigned short* bp0 = L6o + (0 * 16 + c) * 136 + q * 8;
            const unsigned short* bp1 = L6o + (1 * 16 + c) * 136 + q * 8;
            f32x4 acc0 = {0.f,0.f,0.f,0.f}, acc1 = {0.f,0.f,0.f,0.f};
            mfma_tile_f32A<128>(a0f, a1f, bp0, bp1, acc0, acc1);
            epilogue_store(P.X8 + ((size_t)sl * 128 + bg * 16 + c) * 256 + f0 + q * 4,
                           acc0, acc1, B7L, f0 + q * 4, s0, s1);
        }
    }
}

// ============================================================================
// Flat MFMA layer (L8..L11): verified body (verbatim).
// ============================================================================
template<int CIN, int CF, int NP, int MW, int NW>
__global__ __launch_bounds__(256) void mfma_kernel(
    const unsigned short* __restrict__ Xin,
    const unsigned short* __restrict__ Wb,
    const float* __restrict__ bias,
    const int*   __restrict__ sel,
    unsigned short* __restrict__ Xout)
{
    constexpr int FT = CF / (16 * MW);
    constexpr int BT = 128 / (16 * NW);

    const int wid  = threadIdx.x >> 6;
    const int lane = threadIdx.x & 63;
    const int task = blockIdx.x * 4 + wid;
    const int bi = task % BT;
    const int fi = (task / BT) % FT;
    const int n  = task / (BT * FT);

    const int c = lane & 15;
    const int q = lane >> 4;
    const int s0 = __builtin_amdgcn_readfirstlane(sel[2 * n]);
    const int s1 = __builtin_amdgcn_readfirstlane(sel[2 * n + 1]);

    const int f0 = fi * 16 * MW;
    const int b0 = bi * 16 * NW;

    const unsigned short* ap[2][MW];
    const unsigned short* bp[2][NW];
#pragma unroll
    for (int p = 0; p < 2; ++p) {
        int s = p ? s1 : s0;
#pragma unroll
        for (int mi = 0; mi < MW; ++mi)
            ap[p][mi] = Wb + (size_t)((f0 + mi * 16 + c) * 3 + s) * CIN + q * 8;
#pragma unroll
        for (int ni = 0; ni < NW; ++ni)
            bp[p][ni] = Xin + ((size_t)(2 * n + p) * 128 + b0 + ni * 16 + c) * CIN + q * 8;
    }

    f32x4 acc[2][MW][NW];
#pragma unroll
    for (int p = 0; p < 2; ++p)
#pragma unroll
        for (int mi = 0; mi < MW; ++mi)
#pragma unroll
            for (int ni = 0; ni < NW; ++ni)
                acc[p][mi][ni] = (f32x4){0.f, 0.f, 0.f, 0.f};

#pragma unroll 2
    for (int k = 0; k < CIN; k += 32) {
        bf16x8 A[2][MW], B[2][NW];
#pragma unroll
        for (int p = 0; p < 2; ++p) {
#pragma unroll
            for (int mi = 0; mi < MW; ++mi)
                A[p][mi] = __builtin_bit_cast(bf16x8, *(const float4*)(const void*)(ap[p][mi] + k));
#pragma unroll
            for (int ni = 0; ni < NW; ++ni)
                B[p][ni] = __builtin_bit_cast(bf16x8, *(const float4*)(const void*)(bp[p][ni] + k));
        }
#pragma unroll
        for (int p = 0; p < 2; ++p)
#pragma unroll
            for (int mi = 0; mi < MW; ++mi)
#pragma unroll
                for (int ni = 0; ni < NW; ++ni)
                    acc[p][mi][ni] = __builtin_amdgcn_mfma_f32_16x16x32_bf16(
                        A[p][mi], B[p][ni], acc[p][mi][ni], 0, 0, 0);
    }

#pragma unroll
    for (int mi = 0; mi < MW; ++mi) {
        int fbase = f0 + mi * 16 + q * 4;
#pragma unroll
        for (int ni = 0; ni < NW; ++ni) {
            int b = b0 + ni * 16 + c;
            epilogue_store(Xout + ((size_t)n * 128 + b) * CF + fbase,
                           acc[0][mi][ni], acc[1][mi][ni], bias, fbase, s0, s1);
        }
    }
}

// ============================================================================
// FC head: h bf16 [128][1024]; out [128][16] fp32 log-softmax (verbatim)
// ============================================================================
__global__ __launch_bounds__(256) void fc_logsoftmax_kernel(
    const unsigned short* __restrict__ h, const float* __restrict__ fcW,
    const float* __restrict__ fcb, float* __restrict__ out)
{
    int b   = blockIdx.x;
    int tid = threadIdx.x;
    int k     = tid & 15;
    int chunk = tid >> 4;

    const float* __restrict__ wk = fcW + (size_t)k * 1024;
    const unsigned short* hb = h + (size_t)b * 1024;

    float partial = 0.0f;
    int j0 = chunk * 64;
#pragma unroll 8
    for (int j = 0; j < 64; ++j)
        partial = fmaf(bf2f(hb[j0 + j]), wk[j0 + j], partial);

    __shared__ float red[16][17];
    red[chunk][k] = partial;
    __syncthreads();

    __shared__ float logits[16];
    if (tid < 16) {
        float s = fcb[tid];
#pragma unroll
        for (int c = 0; c < 16; ++c) s += red[c][tid];
        logits[tid] = s;
    }
    __syncthreads();

    if (tid < 16) {
        float mx = -INFINITY;
#pragma unroll
        for (int kk = 0; kk < 16; ++kk) mx = fmaxf(mx, logits[kk]);
        float se = 0.0f;
#pragma unroll
        for (int kk = 0; kk < 16; ++kk) se += expf(logits[kk] - mx);
        out[b * 16 + tid] = logits[tid] - mx - logf(se);
    }
}

// ============================================================================
extern "C" void kernel_launch(void* const* d_in, const int* in_sizes, int n_in,
                              void* d_out, int out_size, void* d_ws, size_t ws_size,
                              hipStream_t stream)
{
#define WL(i) (const float*)d_in[1 + 3 * (i)]
#define BL(i) (const float*)d_in[2 + 3 * (i)]
#define SL(i) (const int*)  d_in[3 + 3 * (i)]

    unsigned short* bufA = (unsigned short*)d_ws;          // 4 MB
    unsigned short* bufB = bufA + 2u * 1024u * 1024u;      // 4 MB
    unsigned short* X3   = bufB + 2u * 1024u * 1024u;      // 4 MB [512][128][32]
    unsigned short* Wb   = X3   + 2u * 1024u * 1024u;      // packed bf16 (W8..W11)

    // ---- K1: streaming L1+L2 -> X3  ||  pack W8..W11 + touch W3..W7 ----
    HeadParams HP;
    HP.x  = (const float*)d_in[0];
    HP.W1 = WL(0); HP.B1 = BL(0); HP.S1 = SL(0);
    HP.W2 = WL(1); HP.B2 = BL(1); HP.S2 = SL(1);
    for (int i = 0; i < 9; ++i) HP.Wsrc[i] = WL(2 + i);
    HP.Wb = Wb; HP.X3 = X3;
    head_l12_pack<<<512, 256, 0, stream>>>(HP);

    // ---- K2: L3..L7 -> X8 (bufA) ----
    KBParams KB;
    for (int i = 0; i < 9; ++i) {
        KB.Wsrc[i] = WL(2 + i);
        KB.Bl[i]   = BL(2 + i);
        KB.Sl[i]   = SL(2 + i);
    }
    KB.X3 = X3; KB.X8 = bufA;
    kb_l37<<<128, 512, 0, stream>>>(KB);

    // ---- tails: flat MFMA layers L8..L11 ----
    mfma_kernel<256, 512, 8, 2, 2><<<128, 256, 0, stream>>>(bufA, Wb + O_W8,  BL(7),  SL(7),  bufB);
    mfma_kernel<512, 512, 4, 1, 1><<<256, 256, 0, stream>>>(bufB, Wb + O_W9,  BL(8),  SL(8),  bufA);
    mfma_kernel<512, 512, 2, 1, 1><<<128, 256, 0, stream>>>(bufA, Wb + O_W10, BL(9),  SL(9),  bufB);
    mfma_kernel<512, 1024, 1, 1, 1><<<128, 256, 0, stream>>>(bufB, Wb + O_W11, BL(10), SL(10), bufA);

    // ---- FC ----
    fc_logsoftmax_kernel<<<128, 256, 0, stream>>>(bufA, (const float*)d_in[34], (const float*)d_in[35], (float*)d_out);

#undef WL
#undef BL
#undef SL
}

// Round 9
// 205.329 us; speedup vs baseline: 1.4549x; 1.0533x over previous
//
#include <hip/hip_runtime.h>
#include <math.h>

typedef __attribute__((ext_vector_type(8))) short bf16x8;
typedef __attribute__((ext_vector_type(4))) float f32x4;

__device__ __forceinline__ unsigned short f2bf(float f) {
    unsigned u = __builtin_bit_cast(unsigned, f);
    u += 0x7FFF + ((u >> 16) & 1);          // RNE
    return (unsigned short)(u >> 16);
}
__device__ __forceinline__ float bf2f(unsigned short h) {
    unsigned u = ((unsigned)h) << 16;
    return __builtin_bit_cast(float, u);
}

// Packed-weight offsets inside Wb (bf16 elements), W3..W11 cumulative
#define O_W3 0
#define O_W4 6144
#define O_W5 18432
#define O_W6 30720
#define O_W7 55296
#define O_W8 153600
#define O_W9 546816
#define O_W10 1333248
#define O_W11 2119680

// ============================================================================
// MFMA helpers (verified R9/R11/R12 prev session; R0 fast-path this session)
// ============================================================================
template<int CIN>
__device__ __forceinline__ void mfma_tile(
    const unsigned short* a0, const unsigned short* a1,
    const unsigned short* b0p, const unsigned short* b1p,
    f32x4& acc0, f32x4& acc1)
{
#pragma unroll
    for (int k = 0; k < CIN; k += 32) {
        bf16x8 A0 = __builtin_bit_cast(bf16x8, *(const float4*)(const void*)(a0 + k));
        bf16x8 A1 = __builtin_bit_cast(bf16x8, *(const float4*)(const void*)(a1 + k));
        bf16x8 B0 = __builtin_bit_cast(bf16x8, *(const float4*)(const void*)(b0p + k));
        bf16x8 B1 = __builtin_bit_cast(bf16x8, *(const float4*)(const void*)(b1p + k));
        acc0 = __builtin_amdgcn_mfma_f32_16x16x32_bf16(A0, B0, acc0, 0, 0, 0);
        acc1 = __builtin_amdgcn_mfma_f32_16x16x32_bf16(A1, B1, acc1, 0, 0, 0);
    }
}

__device__ __forceinline__ void epilogue_store(
    unsigned short* dst, const f32x4& acc0, const f32x4& acc1,
    const float* bias, int fbase, int s0, int s1)
{
    unsigned short o[4];
#pragma unroll
    for (int r = 0; r < 4; ++r) {
        float v = fmaxf(fmaxf(acc0[r] + bias[(fbase + r) * 3 + s0],
                              acc1[r] + bias[(fbase + r) * 3 + s1]), 0.f);
        o[r] = f2bf(v);
    }
    *(ushort4*)dst = make_ushort4(o[0], o[1], o[2], o[3]);
}

// ============================================================================
// HEAD (R8-proven streaming shape, ~5 us): L1+L2 with no inter-wave coupling
//   blocks 0..255  : 1024 independent waves; lane owns np2; X3 out.
//   blocks 256..511: pack W3..W11 fp32 -> bf16 (extended from R8's W8..W11).
// ============================================================================
struct HeadParams {
    const float* x;
    const float* W1; const float* B1; const int* S1;
    const float* W2; const float* B2; const int* S2;
    const float* Wsrc[9];          // W3..W11 fp32
    unsigned short* Wb;
    unsigned short* X3;            // [512][128][32]
};

__global__ __launch_bounds__(256) void head_l12_pack(HeadParams P)
{
    const int tid = threadIdx.x;

    if (blockIdx.x >= 256) {
        // ---- pack W3..W11 (21.3 MB stream over 65536 threads) ----
        int gt = (blockIdx.x - 256) * 256 + tid;      // 0..65535
        const int we[9] = {6144, 12288, 12288, 24576, 98304, 393216, 786432, 786432, 1572864};
        const int wo[9] = {O_W3, O_W4, O_W5, O_W6, O_W7, O_W8, O_W9, O_W10, O_W11};
#pragma unroll
        for (int li = 0; li < 9; ++li) {
            const float4* src = (const float4*)P.Wsrc[li];
            ushort4* dst = (ushort4*)(P.Wb + wo[li]);
            int n4 = we[li] >> 2;
            for (int i = gt; i < n4; i += 65536) {
                float4 w = src[i];
                dst[i] = make_ushort4(f2bf(w.x), f2bf(w.y), f2bf(w.z), f2bf(w.w));
            }
        }
        return;
    }

    // ---- stage L1/L2 weights (3.75 KB), one barrier ----
    __shared__ float wsm[960];
    for (int i = tid; i < 960; i += 256) {
        float v;
        if (i < 72)       v = P.W1[i];
        else if (i < 96)  v = P.B1[i - 72];
        else if (i < 864) v = P.W2[i - 96];
        else              v = P.B2[i - 864];
        wsm[i] = v;
    }
    __syncthreads();

    const float* wl1 = wsm;
    const float* bl1 = wsm + 72;
    const float* wl2 = wsm + 96;
    const float* bl2 = wsm + 864;

    const int lane = tid & 63;
    const int gw   = blockIdx.x * 4 + (tid >> 6);   // 0..1023
    const int b    = gw >> 3;                        // 0..127
    const int chunk= gw & 7;                         // 0..7
    const int np2  = chunk * 64 + lane;              // 0..511

    const float* xb = P.x + (size_t)b * 6144 + chunk * 256 + 4 * lane;
    float4 x0 = *(const float4*)(xb);            // ch0, positions 4np2..+3
    float4 x1 = *(const float4*)(xb + 2048);     // ch1
    float4 x2 = *(const float4*)(xb + 4096);     // ch2
    int4 sA = *(const int4*)(P.S1 + 4 * np2);    // S1[4np2..4np2+3]
    int2 sB = *(const int2*)(P.S2 + 2 * np2);    // S2[2np2..2np2+1]

    // ---- L1 (cf=8, cin=3), bf16 round-trip preserved ----
    float y1a[8], y1b[8];
    {
        int s0 = sA.x, s1 = sA.y;
#pragma unroll
        for (int f = 0; f < 8; ++f) {
            int r0 = f * 3 + s0, r1 = f * 3 + s1;
            float z0 = fmaf(wl1[r0*3+2], x2.x, fmaf(wl1[r0*3+1], x1.x, fmaf(wl1[r0*3+0], x0.x, bl1[r0])));
            float z1 = fmaf(wl1[r1*3+2], x2.y, fmaf(wl1[r1*3+1], x1.y, fmaf(wl1[r1*3+0], x0.y, bl1[r1])));
            y1a[f] = bf2f(f2bf(fmaxf(fmaxf(z0, z1), 0.f)));
        }
        int t0 = sA.z, t1 = sA.w;
#pragma unroll
        for (int f = 0; f < 8; ++f) {
            int r0 = f * 3 + t0, r1 = f * 3 + t1;
            float z0 = fmaf(wl1[r0*3+2], x2.z, fmaf(wl1[r0*3+1], x1.z, fmaf(wl1[r0*3+0], x0.z, bl1[r0])));
            float z1 = fmaf(wl1[r1*3+2], x2.w, fmaf(wl1[r1*3+1], x1.w, fmaf(wl1[r1*3+0], x0.w, bl1[r1])));
            y1b[f] = bf2f(f2bf(fmaxf(fmaxf(z0, z1), 0.f)));
        }
    }

    // ---- L2 (cf=32, cin=8) ----
    unsigned short o[32];
    {
        int s0 = sB.x, s1 = sB.y;
#pragma unroll
        for (int f = 0; f < 32; ++f) {
            const float* w0 = &wl2[(f * 3 + s0) * 8];
            const float* w1 = &wl2[(f * 3 + s1) * 8];
            float z0 = bl2[f * 3 + s0], z1 = bl2[f * 3 + s1];
#pragma unroll
            for (int k = 0; k < 8; ++k) {
                z0 = fmaf(w0[k], y1a[k], z0);
                z1 = fmaf(w1[k], y1b[k], z1);
            }
            o[f] = f2bf(fmaxf(fmaxf(z0, z1), 0.f));
        }
    }

    unsigned short* dst = P.X3 + ((size_t)np2 * 128 + b) * 32;
#pragma unroll
    for (int i2 = 0; i2 < 8; ++i2)
        *(ushort4*)(dst + 4 * i2) = make_ushort4(o[4*i2], o[4*i2+1], o[4*i2+2], o[4*i2+3]);
}

// ============================================================================
// stage2: L3+L4+L5 fused (R0-VERBATIM, proven fast). 256 blocks x 256 thr.
// W from GLOBAL packed Wb (bf16). LDS intermediates padded (stride 72).
// X3 [512][128][32] -> X6 [64][128][64]
// ============================================================================
__global__ __launch_bounds__(256) void stage2_kernel(
    const unsigned short* __restrict__ X3,
    const unsigned short* __restrict__ Wb,   // W3@0, W4@6144, W5@18432
    const float* __restrict__ B3, const int* __restrict__ S3,
    const float* __restrict__ B4, const int* __restrict__ S4,
    const float* __restrict__ B5, const int* __restrict__ S5,
    unsigned short* __restrict__ X6)
{
    constexpr int RPE = 72;
    __shared__ unsigned short L3o[4 * 32 * RPE];
    __shared__ unsigned short L4o[2 * 32 * RPE];

    const int tid  = threadIdx.x;
    const int lane = tid & 63;
    const int wv   = tid >> 6;
    const int c = lane & 15, q = lane >> 4;
    const int n5 = blockIdx.x >> 2;
    const int b0 = (blockIdx.x & 3) * 32;

    const unsigned short* W3b = Wb;
    const unsigned short* W4b = Wb + 6144;
    const unsigned short* W5b = Wb + 18432;

    for (int t = wv; t < 32; t += 4) {
        int bt = t & 1, ft = (t >> 1) & 3, j = t >> 3;
        int np = 4 * n5 + j;
        int s0 = __builtin_amdgcn_readfirstlane(S3[2 * np]);
        int s1 = __builtin_amdgcn_readfirstlane(S3[2 * np + 1]);
        int f0 = ft * 16, bl = bt * 16;
        const unsigned short* a0 = W3b + (size_t)((f0 + c) * 3 + s0) * 32 + q * 8;
        const unsigned short* a1 = W3b + (size_t)((f0 + c) * 3 + s1) * 32 + q * 8;
        const unsigned short* bp0 = X3 + ((size_t)(8 * n5 + 2 * j) * 128 + b0 + bl + c) * 32 + q * 8;
        const unsigned short* bp1 = X3 + ((size_t)(8 * n5 + 2 * j + 1) * 128 + b0 + bl + c) * 32 + q * 8;
        f32x4 acc0 = {0.f,0.f,0.f,0.f}, acc1 = {0.f,0.f,0.f,0.f};
        mfma_tile<32>(a0, a1, bp0, bp1, acc0, acc1);
        epilogue_store(&L3o[((size_t)j * 32 + bl + c) * RPE + f0 + q * 4],
                       acc0, acc1, B3, f0 + q * 4, s0, s1);
    }
    __syncthreads();

    for (int t = wv; t < 16; t += 4) {
        int bt = t & 1, ft = (t >> 1) & 3, j = t >> 3;
        int np = 2 * n5 + j;
        int s0 = __builtin_amdgcn_readfirstlane(S4[2 * np]);
        int s1 = __builtin_amdgcn_readfirstlane(S4[2 * np + 1]);
        int f0 = ft * 16, bl = bt * 16;
        const unsigned short* a0 = W4b + (size_t)((f0 + c) * 3 + s0) * 64 + q * 8;
        const unsigned short* a1 = W4b + (size_t)((f0 + c) * 3 + s1) * 64 + q * 8;
        const unsigned short* bp0 = &L3o[((size_t)(2 * j) * 32 + bl + c) * RPE + q * 8];
        const unsigned short* bp1 = &L3o[((size_t)(2 * j + 1) * 32 + bl + c) * RPE + q * 8];
        f32x4 acc0 = {0.f,0.f,0.f,0.f}, acc1 = {0.f,0.f,0.f,0.f};
        mfma_tile<64>(a0, a1, bp0, bp1, acc0, acc1);
        epilogue_store(&L4o[((size_t)j * 32 + bl + c) * RPE + f0 + q * 4],
                       acc0, acc1, B4, f0 + q * 4, s0, s1);
    }
    __syncthreads();

    for (int t = wv; t < 8; t += 4) {
        int bt = t & 1, ft = t >> 1;
        int s0 = __builtin_amdgcn_readfirstlane(S5[2 * n5]);
        int s1 = __builtin_amdgcn_readfirstlane(S5[2 * n5 + 1]);
        int f0 = ft * 16, bl = bt * 16;
        const unsigned short* a0 = W5b + (size_t)((f0 + c) * 3 + s0) * 64 + q * 8;
        const unsigned short* a1 = W5b + (size_t)((f0 + c) * 3 + s1) * 64 + q * 8;
        const unsigned short* bp0 = &L4o[((size_t)(0) * 32 + bl + c) * RPE + q * 8];
        const unsigned short* bp1 = &L4o[((size_t)(1) * 32 + bl + c) * RPE + q * 8];
        f32x4 acc0 = {0.f,0.f,0.f,0.f}, acc1 = {0.f,0.f,0.f,0.f};
        mfma_tile<64>(a0, a1, bp0, bp1, acc0, acc1);
        epilogue_store(X6 + ((size_t)n5 * 128 + b0 + bl + c) * 64 + f0 + q * 4,
                       acc0, acc1, B5, f0 + q * 4, s0, s1);
    }
}

// ============================================================================
// stage67: L6+L7 fused (R0-VERBATIM, proven fast). 128 blocks x 512 thr.
// X6 [64][128][64] -> X8 [16][128][256]
// ============================================================================
__global__ __launch_bounds__(512) void stage67_kernel(
    const unsigned short* __restrict__ X6,
    const unsigned short* __restrict__ W6b, const float* __restrict__ B6, const int* __restrict__ S6,
    const unsigned short* __restrict__ W7b, const float* __restrict__ B7, const int* __restrict__ S7,
    unsigned short* __restrict__ X8)
{
    constexpr int RPE = 136;                       // 128 + 8 pad
    __shared__ unsigned short L6o[2 * 16 * RPE];   // 8.7 KB

    const int tid  = threadIdx.x;
    const int lane = tid & 63;
    const int wv   = tid >> 6;                     // 0..7
    const int c = lane & 15, q = lane >> 4;
    const int n7 = blockIdx.x >> 3;                // 0..15
    const int b0 = (blockIdx.x & 7) * 16;

    // ---- L6 (CIN=64, CF=128): out pos 2n7+j (j=0,1), 8 f-tiles each ----
    for (int t = wv; t < 16; t += 8) {
        int j = t >> 3, ft = t & 7;
        int np = 2 * n7 + j;
        int s0 = __builtin_amdgcn_readfirstlane(S6[2 * np]);
        int s1 = __builtin_amdgcn_readfirstlane(S6[2 * np + 1]);
        int f0 = ft * 16;
        const unsigned short* a0 = W6b + (size_t)((f0 + c) * 3 + s0) * 64 + q * 8;
        const unsigned short* a1 = W6b + (size_t)((f0 + c) * 3 + s1) * 64 + q * 8;
        const unsigned short* bp0 = X6 + ((size_t)(2 * np) * 128 + b0 + c) * 64 + q * 8;
        const unsigned short* bp1 = X6 + ((size_t)(2 * np + 1) * 128 + b0 + c) * 64 + q * 8;
        f32x4 acc0 = {0.f,0.f,0.f,0.f}, acc1 = {0.f,0.f,0.f,0.f};
        mfma_tile<64>(a0, a1, bp0, bp1, acc0, acc1);
        epilogue_store(&L6o[((size_t)j * 16 + c) * RPE + f0 + q * 4],
                       acc0, acc1, B6, f0 + q * 4, s0, s1);
    }
    __syncthreads();

    // ---- L7 (CIN=128, CF=256): out pos n7, 16 f-tiles ----
    {
        int s0 = __builtin_amdgcn_readfirstlane(S7[2 * n7]);
        int s1 = __builtin_amdgcn_readfirstlane(S7[2 * n7 + 1]);
        for (int t = wv; t < 16; t += 8) {
            int f0 = t * 16;
            const unsigned short* a0 = W7b + (size_t)((f0 + c) * 3 + s0) * 128 + q * 8;
            const unsigned short* a1 = W7b + (size_t)((f0 + c) * 3 + s1) * 128 + q * 8;
            const unsigned short* bp0 = &L6o[((size_t)(0) * 16 + c) * RPE + q * 8];
            const unsigned short* bp1 = &L6o[((size_t)(1) * 16 + c) * RPE + q * 8];
            f32x4 acc0 = {0.f,0.f,0.f,0.f}, acc1 = {0.f,0.f,0.f,0.f};
            mfma_tile<128>(a0, a1, bp0, bp1, acc0, acc1);
            epilogue_store(X8 + ((size_t)n7 * 128 + b0 + c) * 256 + f0 + q * 4,
                           acc0, acc1, B7, f0 + q * 4, s0, s1);
        }
    }
}

// ============================================================================
// Flat MFMA layer (L8..L11): verified body (verbatim).
// ============================================================================
template<int CIN, int CF, int NP, int MW, int NW>
__global__ __launch_bounds__(256) void mfma_kernel(
    const unsigned short* __restrict__ Xin,
    const unsigned short* __restrict__ Wb,
    const float* __restrict__ bias,
    const int*   __restrict__ sel,
    unsigned short* __restrict__ Xout)
{
    constexpr int FT = CF / (16 * MW);
    constexpr int BT = 128 / (16 * NW);

    const int wid  = threadIdx.x >> 6;
    const int lane = threadIdx.x & 63;
    const int task = blockIdx.x * 4 + wid;
    const int bi = task % BT;
    const int fi = (task / BT) % FT;
    const int n  = task / (BT * FT);

    const int c = lane & 15;
    const int q = lane >> 4;
    const int s0 = __builtin_amdgcn_readfirstlane(sel[2 * n]);
    const int s1 = __builtin_amdgcn_readfirstlane(sel[2 * n + 1]);

    const int f0 = fi * 16 * MW;
    const int b0 = bi * 16 * NW;

    const unsigned short* ap[2][MW];
    const unsigned short* bp[2][NW];
#pragma unroll
    for (int p = 0; p < 2; ++p) {
        int s = p ? s1 : s0;
#pragma unroll
        for (int mi = 0; mi < MW; ++mi)
            ap[p][mi] = Wb + (size_t)((f0 + mi * 16 + c) * 3 + s) * CIN + q * 8;
#pragma unroll
        for (int ni = 0; ni < NW; ++ni)
            bp[p][ni] = Xin + ((size_t)(2 * n + p) * 128 + b0 + ni * 16 + c) * CIN + q * 8;
    }

    f32x4 acc[2][MW][NW];
#pragma unroll
    for (int p = 0; p < 2; ++p)
#pragma unroll
        for (int mi = 0; mi < MW; ++mi)
#pragma unroll
            for (int ni = 0; ni < NW; ++ni)
                acc[p][mi][ni] = (f32x4){0.f, 0.f, 0.f, 0.f};

#pragma unroll 2
    for (int k = 0; k < CIN; k += 32) {
        bf16x8 A[2][MW], B[2][NW];
#pragma unroll
        for (int p = 0; p < 2; ++p) {
#pragma unroll
            for (int mi = 0; mi < MW; ++mi)
                A[p][mi] = __builtin_bit_cast(bf16x8, *(const float4*)(const void*)(ap[p][mi] + k));
#pragma unroll
            for (int ni = 0; ni < NW; ++ni)
                B[p][ni] = __builtin_bit_cast(bf16x8, *(const float4*)(const void*)(bp[p][ni] + k));
        }
#pragma unroll
        for (int p = 0; p < 2; ++p)
#pragma unroll
            for (int mi = 0; mi < MW; ++mi)
#pragma unroll
                for (int ni = 0; ni < NW; ++ni)
                    acc[p][mi][ni] = __builtin_amdgcn_mfma_f32_16x16x32_bf16(
                        A[p][mi], B[p][ni], acc[p][mi][ni], 0, 0, 0);
    }

#pragma unroll
    for (int mi = 0; mi < MW; ++mi) {
        int fbase = f0 + mi * 16 + q * 4;
#pragma unroll
        for (int ni = 0; ni < NW; ++ni) {
            int b = b0 + ni * 16 + c;
            epilogue_store(Xout + ((size_t)n * 128 + b) * CF + fbase,
                           acc[0][mi][ni], acc[1][mi][ni], bias, fbase, s0, s1);
        }
    }
}

// ============================================================================
// FC head: h bf16 [128][1024]; out [128][16] fp32 log-softmax (verbatim)
// ============================================================================
__global__ __launch_bounds__(256) void fc_logsoftmax_kernel(
    const unsigned short* __restrict__ h, const float* __restrict__ fcW,
    const float* __restrict__ fcb, float* __restrict__ out)
{
    int b   = blockIdx.x;
    int tid = threadIdx.x;
    int k     = tid & 15;
    int chunk = tid >> 4;

    const float* __restrict__ wk = fcW + (size_t)k * 1024;
    const unsigned short* hb = h + (size_t)b * 1024;

    float partial = 0.0f;
    int j0 = chunk * 64;
#pragma unroll 8
    for (int j = 0; j < 64; ++j)
        partial = fmaf(bf2f(hb[j0 + j]), wk[j0 + j], partial);

    __shared__ float red[16][17];
    red[chunk][k] = partial;
    __syncthreads();

    __shared__ float logits[16];
    if (tid < 16) {
        float s = fcb[tid];
#pragma unroll
        for (int c = 0; c < 16; ++c) s += red[c][tid];
        logits[tid] = s;
    }
    __syncthreads();

    if (tid < 16) {
        float mx = -INFINITY;
#pragma unroll
        for (int kk = 0; kk < 16; ++kk) mx = fmaxf(mx, logits[kk]);
        float se = 0.0f;
#pragma unroll
        for (int kk = 0; kk < 16; ++kk) se += expf(logits[kk] - mx);
        out[b * 16 + tid] = logits[tid] - mx - logf(se);
    }
}

// ============================================================================
extern "C" void kernel_launch(void* const* d_in, const int* in_sizes, int n_in,
                              void* d_out, int out_size, void* d_ws, size_t ws_size,
                              hipStream_t stream)
{
#define WL(i) (const float*)d_in[1 + 3 * (i)]
#define BL(i) (const float*)d_in[2 + 3 * (i)]
#define SL(i) (const int*)  d_in[3 + 3 * (i)]

    unsigned short* bufA = (unsigned short*)d_ws;          // 4 MB
    unsigned short* bufB = bufA + 2u * 1024u * 1024u;      // 4 MB
    unsigned short* X3   = bufB + 2u * 1024u * 1024u;      // 4 MB [512][128][32]
    unsigned short* Wb   = X3   + 2u * 1024u * 1024u;      // packed bf16 W3..W11

    // ---- K1: streaming L1+L2 -> X3  ||  pack W3..W11 -> Wb ----
    HeadParams HP;
    HP.x  = (const float*)d_in[0];
    HP.W1 = WL(0); HP.B1 = BL(0); HP.S1 = SL(0);
    HP.W2 = WL(1); HP.B2 = BL(1); HP.S2 = SL(1);
    for (int i = 0; i < 9; ++i) HP.Wsrc[i] = WL(2 + i);
    HP.Wb = Wb; HP.X3 = X3;
    head_l12_pack<<<512, 256, 0, stream>>>(HP);

    // ---- K2: L3+L4+L5 -> X6 (bufB)  [R0-verbatim fast path] ----
    stage2_kernel<<<256, 256, 0, stream>>>(X3, Wb,
        BL(2), SL(2), BL(3), SL(3), BL(4), SL(4), bufB);

    // ---- K3: L6+L7 -> X8 (bufA)  [R0-verbatim fast path] ----
    stage67_kernel<<<128, 512, 0, stream>>>(bufB,
        Wb + O_W6, BL(5), SL(5), Wb + O_W7, BL(6), SL(6), bufA);

    // ---- K4..K7: flat MFMA layers L8..L11 ----
    mfma_kernel<256, 512, 8, 2, 2><<<128, 256, 0, stream>>>(bufA, Wb + O_W8,  BL(7),  SL(7),  bufB);
    mfma_kernel<512, 512, 4, 1, 1><<<256, 256, 0, stream>>>(bufB, Wb + O_W9,  BL(8),  SL(8),  bufA);
    mfma_kernel<512, 512, 2, 1, 1><<<128, 256, 0, stream>>>(bufA, Wb + O_W10, BL(9),  SL(9),  bufB);
    mfma_kernel<512, 1024, 1, 1, 1><<<128, 256, 0, stream>>>(bufB, Wb + O_W11, BL(10), SL(10), bufA);

    // ---- K8: FC ----
    fc_logsoftmax_kernel<<<128, 256, 0, stream>>>(bufA, (const float*)d_in[34], (const float*)d_in[35], (float*)d_out);

#undef WL
#undef BL
#undef SL
}

// Round 10
// 198.821 us; speedup vs baseline: 1.5026x; 1.0327x over previous
//
#include <hip/hip_runtime.h>
#include <math.h>

typedef __attribute__((ext_vector_type(8))) short bf16x8;
typedef __attribute__((ext_vector_type(4))) float f32x4;

__device__ __forceinline__ unsigned short f2bf(float f) {
    unsigned u = __builtin_bit_cast(unsigned, f);
    u += 0x7FFF + ((u >> 16) & 1);          // RNE
    return (unsigned short)(u >> 16);
}
__device__ __forceinline__ float bf2f(unsigned short h) {
    unsigned u = ((unsigned)h) << 16;
    return __builtin_bit_cast(float, u);
}

// Packed-weight offsets inside Wb (bf16 elements), W3..W11 cumulative
#define O_W3 0
#define O_W4 6144
#define O_W5 18432
#define O_W6 30720
#define O_W7 55296
#define O_W8 153600
#define O_W9 546816
#define O_W10 1333248
#define O_W11 2119680

// ============================================================================
// MFMA helpers (verified R9/R11/R12 prev session; R0/R9 fast paths this one)
// ============================================================================
template<int CIN>
__device__ __forceinline__ void mfma_tile(
    const unsigned short* a0, const unsigned short* a1,
    const unsigned short* b0p, const unsigned short* b1p,
    f32x4& acc0, f32x4& acc1)
{
#pragma unroll
    for (int k = 0; k < CIN; k += 32) {
        bf16x8 A0 = __builtin_bit_cast(bf16x8, *(const float4*)(const void*)(a0 + k));
        bf16x8 A1 = __builtin_bit_cast(bf16x8, *(const float4*)(const void*)(a1 + k));
        bf16x8 B0 = __builtin_bit_cast(bf16x8, *(const float4*)(const void*)(b0p + k));
        bf16x8 B1 = __builtin_bit_cast(bf16x8, *(const float4*)(const void*)(b1p + k));
        acc0 = __builtin_amdgcn_mfma_f32_16x16x32_bf16(A0, B0, acc0, 0, 0, 0);
        acc1 = __builtin_amdgcn_mfma_f32_16x16x32_bf16(A1, B1, acc1, 0, 0, 0);
    }
}

__device__ __forceinline__ void epilogue_store(
    unsigned short* dst, const f32x4& acc0, const f32x4& acc1,
    const float* bias, int fbase, int s0, int s1)
{
    unsigned short o[4];
#pragma unroll
    for (int r = 0; r < 4; ++r) {
        float v = fmaxf(fmaxf(acc0[r] + bias[(fbase + r) * 3 + s0],
                              acc1[r] + bias[(fbase + r) * 3 + s1]), 0.f);
        o[r] = f2bf(v);
    }
    *(ushort4*)dst = make_ushort4(o[0], o[1], o[2], o[3]);
}

// ============================================================================
// HEAD (R8/R9-proven streaming shape, ~5 us): L1+L2, no inter-wave coupling.
//   blocks 0..255  : 1024 independent waves; lane owns np2; X3 out.
//   blocks 256..511: pack W3..W11 fp32 -> bf16.
// ============================================================================
struct HeadParams {
    const float* x;
    const float* W1; const float* B1; const int* S1;
    const float* W2; const float* B2; const int* S2;
    const float* Wsrc[9];          // W3..W11 fp32
    unsigned short* Wb;
    unsigned short* X3;            // [512][128][32]
};

__global__ __launch_bounds__(256) void head_l12_pack(HeadParams P)
{
    const int tid = threadIdx.x;

    if (blockIdx.x >= 256) {
        int gt = (blockIdx.x - 256) * 256 + tid;      // 0..65535
        const int we[9] = {6144, 12288, 12288, 24576, 98304, 393216, 786432, 786432, 1572864};
        const int wo[9] = {O_W3, O_W4, O_W5, O_W6, O_W7, O_W8, O_W9, O_W10, O_W11};
#pragma unroll
        for (int li = 0; li < 9; ++li) {
            const float4* src = (const float4*)P.Wsrc[li];
            ushort4* dst = (ushort4*)(P.Wb + wo[li]);
            int n4 = we[li] >> 2;
            for (int i = gt; i < n4; i += 65536) {
                float4 w = src[i];
                dst[i] = make_ushort4(f2bf(w.x), f2bf(w.y), f2bf(w.z), f2bf(w.w));
            }
        }
        return;
    }

    __shared__ float wsm[960];
    for (int i = tid; i < 960; i += 256) {
        float v;
        if (i < 72)       v = P.W1[i];
        else if (i < 96)  v = P.B1[i - 72];
        else if (i < 864) v = P.W2[i - 96];
        else              v = P.B2[i - 864];
        wsm[i] = v;
    }
    __syncthreads();

    const float* wl1 = wsm;
    const float* bl1 = wsm + 72;
    const float* wl2 = wsm + 96;
    const float* bl2 = wsm + 864;

    const int lane = tid & 63;
    const int gw   = blockIdx.x * 4 + (tid >> 6);   // 0..1023
    const int b    = gw >> 3;                        // 0..127
    const int chunk= gw & 7;                         // 0..7
    const int np2  = chunk * 64 + lane;              // 0..511

    const float* xb = P.x + (size_t)b * 6144 + chunk * 256 + 4 * lane;
    float4 x0 = *(const float4*)(xb);
    float4 x1 = *(const float4*)(xb + 2048);
    float4 x2 = *(const float4*)(xb + 4096);
    int4 sA = *(const int4*)(P.S1 + 4 * np2);
    int2 sB = *(const int2*)(P.S2 + 2 * np2);

    float y1a[8], y1b[8];
    {
        int s0 = sA.x, s1 = sA.y;
#pragma unroll
        for (int f = 0; f < 8; ++f) {
            int r0 = f * 3 + s0, r1 = f * 3 + s1;
            float z0 = fmaf(wl1[r0*3+2], x2.x, fmaf(wl1[r0*3+1], x1.x, fmaf(wl1[r0*3+0], x0.x, bl1[r0])));
            float z1 = fmaf(wl1[r1*3+2], x2.y, fmaf(wl1[r1*3+1], x1.y, fmaf(wl1[r1*3+0], x0.y, bl1[r1])));
            y1a[f] = bf2f(f2bf(fmaxf(fmaxf(z0, z1), 0.f)));
        }
        int t0 = sA.z, t1 = sA.w;
#pragma unroll
        for (int f = 0; f < 8; ++f) {
            int r0 = f * 3 + t0, r1 = f * 3 + t1;
            float z0 = fmaf(wl1[r0*3+2], x2.z, fmaf(wl1[r0*3+1], x1.z, fmaf(wl1[r0*3+0], x0.z, bl1[r0])));
            float z1 = fmaf(wl1[r1*3+2], x2.w, fmaf(wl1[r1*3+1], x1.w, fmaf(wl1[r1*3+0], x0.w, bl1[r1])));
            y1b[f] = bf2f(f2bf(fmaxf(fmaxf(z0, z1), 0.f)));
        }
    }

    unsigned short o[32];
    {
        int s0 = sB.x, s1 = sB.y;
#pragma unroll
        for (int f = 0; f < 32; ++f) {
            const float* w0 = &wl2[(f * 3 + s0) * 8];
            const float* w1 = &wl2[(f * 3 + s1) * 8];
            float z0 = bl2[f * 3 + s0], z1 = bl2[f * 3 + s1];
#pragma unroll
            for (int k = 0; k < 8; ++k) {
                z0 = fmaf(w0[k], y1a[k], z0);
                z1 = fmaf(w1[k], y1b[k], z1);
            }
            o[f] = f2bf(fmaxf(fmaxf(z0, z1), 0.f));
        }
    }

    unsigned short* dst = P.X3 + ((size_t)np2 * 128 + b) * 32;
#pragma unroll
    for (int i2 = 0; i2 < 8; ++i2)
        *(ushort4*)(dst + 4 * i2) = make_ushort4(o[4*i2], o[4*i2+1], o[4*i2+2], o[4*i2+3]);
}

// ============================================================================
// stage2 v2: L3+L4+L5 fused, re-gridded. 512 blocks (n5 x 8 b-eighths) x 256
// thr (4 waves). Rounds per wave: L3=4, L4=2, L5=1 (was 8/4/2). All loops
// compile-time trip-count -> full unroll, loads issue in parallel.
// Mechanical restriction of the R0-verbatim math (b-tile 32 -> 16).
// X3 [512][128][32] -> X6 [64][128][64]
// ============================================================================
__global__ __launch_bounds__(256) void stage2_kernel(
    const unsigned short* __restrict__ X3,
    const unsigned short* __restrict__ Wb,   // W3@0, W4@6144, W5@18432
    const float* __restrict__ B3, const int* __restrict__ S3,
    const float* __restrict__ B4, const int* __restrict__ S4,
    const float* __restrict__ B5, const int* __restrict__ S5,
    unsigned short* __restrict__ X6)
{
    constexpr int RPE = 72;
    __shared__ unsigned short L3o[4 * 16 * RPE];   //  9216 B
    __shared__ unsigned short L4o[2 * 16 * RPE];   //  4608 B

    const int tid  = threadIdx.x;
    const int lane = tid & 63;
    const int wv   = tid >> 6;                     // 0..3
    const int c = lane & 15, q = lane >> 4;
    const int n5 = blockIdx.x >> 3;                // 0..63
    const int b0 = (blockIdx.x & 7) * 16;

    const unsigned short* W3b = Wb;
    const unsigned short* W4b = Wb + 6144;
    const unsigned short* W5b = Wb + 18432;

    // ---- L3 (cin=32, cf=64): 16 tasks (ft4 x j4), 4 rounds ----
#pragma unroll
    for (int t = wv; t < 16; t += 4) {
        int ft = t & 3, j = t >> 2;
        int np = 4 * n5 + j;
        int s0 = __builtin_amdgcn_readfirstlane(S3[2 * np]);
        int s1 = __builtin_amdgcn_readfirstlane(S3[2 * np + 1]);
        int f0 = ft * 16;
        const unsigned short* a0 = W3b + (size_t)((f0 + c) * 3 + s0) * 32 + q * 8;
        const unsigned short* a1 = W3b + (size_t)((f0 + c) * 3 + s1) * 32 + q * 8;
        const unsigned short* bp0 = X3 + ((size_t)(8 * n5 + 2 * j) * 128 + b0 + c) * 32 + q * 8;
        const unsigned short* bp1 = X3 + ((size_t)(8 * n5 + 2 * j + 1) * 128 + b0 + c) * 32 + q * 8;
        f32x4 acc0 = {0.f,0.f,0.f,0.f}, acc1 = {0.f,0.f,0.f,0.f};
        mfma_tile<32>(a0, a1, bp0, bp1, acc0, acc1);
        epilogue_store(&L3o[((size_t)j * 16 + c) * RPE + f0 + q * 4],
                       acc0, acc1, B3, f0 + q * 4, s0, s1);
    }
    __syncthreads();

    // ---- L4 (cin=64, cf=64): 8 tasks (ft4 x j2), 2 rounds ----
#pragma unroll
    for (int t = wv; t < 8; t += 4) {
        int ft = t & 3, j = t >> 2;
        int np = 2 * n5 + j;
        int s0 = __builtin_amdgcn_readfirstlane(S4[2 * np]);
        int s1 = __builtin_amdgcn_readfirstlane(S4[2 * np + 1]);
        int f0 = ft * 16;
        const unsigned short* a0 = W4b + (size_t)((f0 + c) * 3 + s0) * 64 + q * 8;
        const unsigned short* a1 = W4b + (size_t)((f0 + c) * 3 + s1) * 64 + q * 8;
        const unsigned short* bp0 = &L3o[((size_t)(2 * j) * 16 + c) * RPE + q * 8];
        const unsigned short* bp1 = &L3o[((size_t)(2 * j + 1) * 16 + c) * RPE + q * 8];
        f32x4 acc0 = {0.f,0.f,0.f,0.f}, acc1 = {0.f,0.f,0.f,0.f};
        mfma_tile<64>(a0, a1, bp0, bp1, acc0, acc1);
        epilogue_store(&L4o[((size_t)j * 16 + c) * RPE + f0 + q * 4],
                       acc0, acc1, B4, f0 + q * 4, s0, s1);
    }
    __syncthreads();

    // ---- L5 (cin=64, cf=64): 4 tasks (ft4), 1 round ----
    {
        int ft = wv;
        int s0 = __builtin_amdgcn_readfirstlane(S5[2 * n5]);
        int s1 = __builtin_amdgcn_readfirstlane(S5[2 * n5 + 1]);
        int f0 = ft * 16;
        const unsigned short* a0 = W5b + (size_t)((f0 + c) * 3 + s0) * 64 + q * 8;
        const unsigned short* a1 = W5b + (size_t)((f0 + c) * 3 + s1) * 64 + q * 8;
        const unsigned short* bp0 = &L4o[((size_t)(0) * 16 + c) * RPE + q * 8];
        const unsigned short* bp1 = &L4o[((size_t)(1) * 16 + c) * RPE + q * 8];
        f32x4 acc0 = {0.f,0.f,0.f,0.f}, acc1 = {0.f,0.f,0.f,0.f};
        mfma_tile<64>(a0, a1, bp0, bp1, acc0, acc1);
        epilogue_store(X6 + ((size_t)n5 * 128 + b0 + c) * 64 + f0 + q * 4,
                       acc0, acc1, B5, f0 + q * 4, s0, s1);
    }
}

// ============================================================================
// stage67: L6+L7 fused (R0-VERBATIM shape + unroll). 128 blocks x 512 thr.
// X6 [64][128][64] -> X8 [16][128][256]
// ============================================================================
__global__ __launch_bounds__(512) void stage67_kernel(
    const unsigned short* __restrict__ X6,
    const unsigned short* __restrict__ W6b, const float* __restrict__ B6, const int* __restrict__ S6,
    const unsigned short* __restrict__ W7b, const float* __restrict__ B7, const int* __restrict__ S7,
    unsigned short* __restrict__ X8)
{
    constexpr int RPE = 136;                       // 128 + 8 pad
    __shared__ unsigned short L6o[2 * 16 * RPE];   // 8.7 KB

    const int tid  = threadIdx.x;
    const int lane = tid & 63;
    const int wv   = tid >> 6;                     // 0..7
    const int c = lane & 15, q = lane >> 4;
    const int n7 = blockIdx.x >> 3;                // 0..15
    const int b0 = (blockIdx.x & 7) * 16;

    // ---- L6 (CIN=64, CF=128): 16 tasks, 2 rounds ----
#pragma unroll
    for (int t = wv; t < 16; t += 8) {
        int j = t >> 3, ft = t & 7;
        int np = 2 * n7 + j;
        int s0 = __builtin_amdgcn_readfirstlane(S6[2 * np]);
        int s1 = __builtin_amdgcn_readfirstlane(S6[2 * np + 1]);
        int f0 = ft * 16;
        const unsigned short* a0 = W6b + (size_t)((f0 + c) * 3 + s0) * 64 + q * 8;
        const unsigned short* a1 = W6b + (size_t)((f0 + c) * 3 + s1) * 64 + q * 8;
        const unsigned short* bp0 = X6 + ((size_t)(2 * np) * 128 + b0 + c) * 64 + q * 8;
        const unsigned short* bp1 = X6 + ((size_t)(2 * np + 1) * 128 + b0 + c) * 64 + q * 8;
        f32x4 acc0 = {0.f,0.f,0.f,0.f}, acc1 = {0.f,0.f,0.f,0.f};
        mfma_tile<64>(a0, a1, bp0, bp1, acc0, acc1);
        epilogue_store(&L6o[((size_t)j * 16 + c) * RPE + f0 + q * 4],
                       acc0, acc1, B6, f0 + q * 4, s0, s1);
    }
    __syncthreads();

    // ---- L7 (CIN=128, CF=256): 16 tasks, 2 rounds ----
    {
        int s0 = __builtin_amdgcn_readfirstlane(S7[2 * n7]);
        int s1 = __builtin_amdgcn_readfirstlane(S7[2 * n7 + 1]);
#pragma unroll
        for (int t = wv; t < 16; t += 8) {
            int f0 = t * 16;
            const unsigned short* a0 = W7b + (size_t)((f0 + c) * 3 + s0) * 128 + q * 8;
            const unsigned short* a1 = W7b + (size_t)((f0 + c) * 3 + s1) * 128 + q * 8;
            const unsigned short* bp0 = &L6o[((size_t)(0) * 16 + c) * RPE + q * 8];
            const unsigned short* bp1 = &L6o[((size_t)(1) * 16 + c) * RPE + q * 8];
            f32x4 acc0 = {0.f,0.f,0.f,0.f}, acc1 = {0.f,0.f,0.f,0.f};
            mfma_tile<128>(a0, a1, bp0, bp1, acc0, acc1);
            epilogue_store(X8 + ((size_t)n7 * 128 + b0 + c) * 256 + f0 + q * 4,
                           acc0, acc1, B7, f0 + q * 4, s0, s1);
        }
    }
}

// ============================================================================
// Flat MFMA layer (L8..L11): verified body (verbatim).
// ============================================================================
template<int CIN, int CF, int NP, int MW, int NW>
__global__ __launch_bounds__(256) void mfma_kernel(
    const unsigned short* __restrict__ Xin,
    const unsigned short* __restrict__ Wb,
    const float* __restrict__ bias,
    const int*   __restrict__ sel,
    unsigned short* __restrict__ Xout)
{
    constexpr int FT = CF / (16 * MW);
    constexpr int BT = 128 / (16 * NW);

    const int wid  = threadIdx.x >> 6;
    const int lane = threadIdx.x & 63;
    const int task = blockIdx.x * 4 + wid;
    const int bi = task % BT;
    const int fi = (task / BT) % FT;
    const int n  = task / (BT * FT);

    const int c = lane & 15;
    const int q = lane >> 4;
    const int s0 = __builtin_amdgcn_readfirstlane(sel[2 * n]);
    const int s1 = __builtin_amdgcn_readfirstlane(sel[2 * n + 1]);

    const int f0 = fi * 16 * MW;
    const int b0 = bi * 16 * NW;

    const unsigned short* ap[2][MW];
    const unsigned short* bp[2][NW];
#pragma unroll
    for (int p = 0; p < 2; ++p) {
        int s = p ? s1 : s0;
#pragma unroll
        for (int mi = 0; mi < MW; ++mi)
            ap[p][mi] = Wb + (size_t)((f0 + mi * 16 + c) * 3 + s) * CIN + q * 8;
#pragma unroll
        for (int ni = 0; ni < NW; ++ni)
            bp[p][ni] = Xin + ((size_t)(2 * n + p) * 128 + b0 + ni * 16 + c) * CIN + q * 8;
    }

    f32x4 acc[2][MW][NW];
#pragma unroll
    for (int p = 0; p < 2; ++p)
#pragma unroll
        for (int mi = 0; mi < MW; ++mi)
#pragma unroll
            for (int ni = 0; ni < NW; ++ni)
                acc[p][mi][ni] = (f32x4){0.f, 0.f, 0.f, 0.f};

#pragma unroll 2
    for (int k = 0; k < CIN; k += 32) {
        bf16x8 A[2][MW], B[2][NW];
#pragma unroll
        for (int p = 0; p < 2; ++p) {
#pragma unroll
            for (int mi = 0; mi < MW; ++mi)
                A[p][mi] = __builtin_bit_cast(bf16x8, *(const float4*)(const void*)(ap[p][mi] + k));
#pragma unroll
            for (int ni = 0; ni < NW; ++ni)
                B[p][ni] = __builtin_bit_cast(bf16x8, *(const float4*)(const void*)(bp[p][ni] + k));
        }
#pragma unroll
        for (int p = 0; p < 2; ++p)
#pragma unroll
            for (int mi = 0; mi < MW; ++mi)
#pragma unroll
                for (int ni = 0; ni < NW; ++ni)
                    acc[p][mi][ni] = __builtin_amdgcn_mfma_f32_16x16x32_bf16(
                        A[p][mi], B[p][ni], acc[p][mi][ni], 0, 0, 0);
    }

#pragma unroll
    for (int mi = 0; mi < MW; ++mi) {
        int fbase = f0 + mi * 16 + q * 4;
#pragma unroll
        for (int ni = 0; ni < NW; ++ni) {
            int b = b0 + ni * 16 + c;
            epilogue_store(Xout + ((size_t)n * 128 + b) * CF + fbase,
                           acc[0][mi][ni], acc[1][mi][ni], bias, fbase, s0, s1);
        }
    }
}

// ============================================================================
// FC head: h bf16 [128][1024]; out [128][16] fp32 log-softmax (verbatim)
// ============================================================================
__global__ __launch_bounds__(256) void fc_logsoftmax_kernel(
    const unsigned short* __restrict__ h, const float* __restrict__ fcW,
    const float* __restrict__ fcb, float* __restrict__ out)
{
    int b   = blockIdx.x;
    int tid = threadIdx.x;
    int k     = tid & 15;
    int chunk = tid >> 4;

    const float* __restrict__ wk = fcW + (size_t)k * 1024;
    const unsigned short* hb = h + (size_t)b * 1024;

    float partial = 0.0f;
    int j0 = chunk * 64;
#pragma unroll 8
    for (int j = 0; j < 64; ++j)
        partial = fmaf(bf2f(hb[j0 + j]), wk[j0 + j], partial);

    __shared__ float red[16][17];
    red[chunk][k] = partial;
    __syncthreads();

    __shared__ float logits[16];
    if (tid < 16) {
        float s = fcb[tid];
#pragma unroll
        for (int c = 0; c < 16; ++c) s += red[c][tid];
        logits[tid] = s;
    }
    __syncthreads();

    if (tid < 16) {
        float mx = -INFINITY;
#pragma unroll
        for (int kk = 0; kk < 16; ++kk) mx = fmaxf(mx, logits[kk]);
        float se = 0.0f;
#pragma unroll
        for (int kk = 0; kk < 16; ++kk) se += expf(logits[kk] - mx);
        out[b * 16 + tid] = logits[tid] - mx - logf(se);
    }
}

// ============================================================================
extern "C" void kernel_launch(void* const* d_in, const int* in_sizes, int n_in,
                              void* d_out, int out_size, void* d_ws, size_t ws_size,
                              hipStream_t stream)
{
#define WL(i) (const float*)d_in[1 + 3 * (i)]
#define BL(i) (const float*)d_in[2 + 3 * (i)]
#define SL(i) (const int*)  d_in[3 + 3 * (i)]

    unsigned short* bufA = (unsigned short*)d_ws;          // 4 MB
    unsigned short* bufB = bufA + 2u * 1024u * 1024u;      // 4 MB
    unsigned short* X3   = bufB + 2u * 1024u * 1024u;      // 4 MB [512][128][32]
    unsigned short* Wb   = X3   + 2u * 1024u * 1024u;      // packed bf16 W3..W11

    // ---- K1: streaming L1+L2 -> X3  ||  pack W3..W11 -> Wb ----
    HeadParams HP;
    HP.x  = (const float*)d_in[0];
    HP.W1 = WL(0); HP.B1 = BL(0); HP.S1 = SL(0);
    HP.W2 = WL(1); HP.B2 = BL(1); HP.S2 = SL(1);
    for (int i = 0; i < 9; ++i) HP.Wsrc[i] = WL(2 + i);
    HP.Wb = Wb; HP.X3 = X3;
    head_l12_pack<<<512, 256, 0, stream>>>(HP);

    // ---- K2: L3+L4+L5 -> X6 (bufB)  [v2: 512 blocks, 7 rounds] ----
    stage2_kernel<<<512, 256, 0, stream>>>(X3, Wb,
        BL(2), SL(2), BL(3), SL(3), BL(4), SL(4), bufB);

    // ---- K3: L6+L7 -> X8 (bufA) ----
    stage67_kernel<<<128, 512, 0, stream>>>(bufB,
        Wb + O_W6, BL(5), SL(5), Wb + O_W7, BL(6), SL(6), bufA);

    // ---- K4..K7: flat MFMA layers L8..L11 ----
    mfma_kernel<256, 512, 8, 2, 2><<<128, 256, 0, stream>>>(bufA, Wb + O_W8,  BL(7),  SL(7),  bufB);
    mfma_kernel<512, 512, 4, 1, 1><<<256, 256, 0, stream>>>(bufB, Wb + O_W9,  BL(8),  SL(8),  bufA);
    mfma_kernel<512, 512, 2, 1, 1><<<128, 256, 0, stream>>>(bufA, Wb + O_W10, BL(9),  SL(9),  bufB);
    mfma_kernel<512, 1024, 1, 1, 1><<<128, 256, 0, stream>>>(bufB, Wb + O_W11, BL(10), SL(10), bufA);

    // ---- K8: FC ----
    fc_logsoftmax_kernel<<<128, 256, 0, stream>>>(bufA, (const float*)d_in[34], (const float*)d_in[35], (float*)d_out);

#undef WL
#undef BL
#undef SL
}